// Round 10
// baseline (543.532 us; speedup 1.0000x reference)
//
#include <hip/hip_runtime.h>

// GCN: 2x (h@W -> symmetric-norm neighbor aggregation +bias, relu) -> h@Wl+bl
// N=100000, E=1600000, D=H=64, C=16, fp32 (no fp32 MFMA -> VALU).
// Round 10: XCD feature-sliced aggregation. t' stored as t2[slice][node][8]
// (slice = 8 features = 3.2MB, fits one XCD's 4MB L2). Aggregate blocks pin
// slice = blockIdx&7; dispatch round-robins blocks over XCDs, so each slice
// becomes L2-resident on one XCD (prev: 25.6MB working set thrashed 4MB L2,
// FETCH=193MB/dispatch). Per edge: 8 lanes read 32B contiguous; 8 edges per
// VMEM instr; shfl_xor cross-group reduce per node.

#define WS_ALIGN 256
#define BSHIFT 8            // 256 nodes per bucket
#define MAXBUCK 512         // n=100000 -> nbuck=391

// ---------------- CSR build ----------------

// bucket-level histogram: one global atomic per (block,bucket)
__global__ void k_bhist(const int* __restrict__ dst, int* __restrict__ bhist,
                        int e, int nbuck) {
    __shared__ int hist[MAXBUCK];
    const int CH = 4096;
    int base = blockIdx.x * CH;
    int end = base + CH; if (end > e) end = e;
    for (int t = threadIdx.x; t < nbuck; t += blockDim.x) hist[t] = 0;
    __syncthreads();
    for (int i = base + threadIdx.x; i < end; i += blockDim.x)
        atomicAdd(&hist[dst[i] >> BSHIFT], 1);
    __syncthreads();
    for (int t = threadIdx.x; t < nbuck; t += blockDim.x)
        if (hist[t]) atomicAdd(&bhist[t], hist[t]);
}

// single-block exclusive scan of bucket totals -> gbase (nbuck+1), gcursor
__global__ void k_bscan(const int* __restrict__ bhist, int* __restrict__ gbase,
                        int* __restrict__ gcursor, int e, int nbuck) {
    __shared__ int tmp[MAXBUCK];
    int t = threadIdx.x;                      // blockDim = MAXBUCK
    int v = (t < nbuck) ? bhist[t] : 0;
    tmp[t] = v;
    __syncthreads();
    int x = v;
    #pragma unroll
    for (int d = 1; d < MAXBUCK; d <<= 1) {
        int y = (t >= d) ? tmp[t - d] : 0;
        __syncthreads();
        x += y;
        tmp[t] = x;
        __syncthreads();
    }
    if (t < nbuck) { gbase[t] = x - v; gcursor[t] = x - v; }
    if (t == 0) gbase[nbuck] = e;
}

// partition (src,dst) pairs into bucket-contiguous regions of bpairs
__global__ void k_partition(const int* __restrict__ src, const int* __restrict__ dst,
                            int* __restrict__ gcursor, int2* __restrict__ bpairs,
                            int e, int nbuck) {
    __shared__ int hist[MAXBUCK];
    __shared__ int lbase[MAXBUCK];
    const int CH = 4096;
    int base = blockIdx.x * CH;
    int end = base + CH; if (end > e) end = e;
    for (int t = threadIdx.x; t < nbuck; t += blockDim.x) hist[t] = 0;
    __syncthreads();
    for (int i = base + threadIdx.x; i < end; i += blockDim.x)
        atomicAdd(&hist[dst[i] >> BSHIFT], 1);
    __syncthreads();
    for (int t = threadIdx.x; t < nbuck; t += blockDim.x) {
        int c = hist[t];
        lbase[t] = (c > 0) ? atomicAdd(&gcursor[t], c) : 0;
        hist[t] = 0;                              // reuse as local cursor
    }
    __syncthreads();
    for (int i = base + threadIdx.x; i < end; i += blockDim.x) {
        int s = src[i], d = dst[i];
        int b = d >> BSHIFT;
        int p = lbase[b] + atomicAdd(&hist[b], 1);
        bpairs[p] = make_int2(s, d);
    }
}

// per-bucket finalize: node counts (LDS), 256-entry exclusive scan (LDS),
// ocnt/inv global write, then exact scatter with LDS cursors.
__global__ void k_bfin(const int2* __restrict__ bpairs, const int* __restrict__ gbase,
                       int2* __restrict__ ocnt, float* __restrict__ inv,
                       int* __restrict__ ssrc, int n) {
    __shared__ int lcnt[256];
    __shared__ int tmp[256];
    __shared__ int loff[256];
    __shared__ int lcur[256];
    const int b = blockIdx.x;
    const int t = threadIdx.x;                 // blockDim = 256
    const int lo = gbase[b];
    const int hi = gbase[b + 1];
    lcnt[t] = 0; lcur[t] = 0;
    __syncthreads();
    for (int i = lo + t; i < hi; i += 256)
        atomicAdd(&lcnt[bpairs[i].y & 255], 1);
    __syncthreads();
    // exclusive scan of lcnt
    int v = lcnt[t];
    tmp[t] = v;
    __syncthreads();
    int x = v;
    #pragma unroll
    for (int d = 1; d < 256; d <<= 1) {
        int y = (t >= d) ? tmp[t - d] : 0;
        __syncthreads();
        x += y;
        tmp[t] = x;
        __syncthreads();
    }
    loff[t] = x - v;
    int node = (b << BSHIFT) + t;
    if (node < n) {
        ocnt[node] = make_int2(lo + (x - v), v);
        inv[node] = rsqrtf((float)v + 1.0f);
    }
    __syncthreads();
    for (int i = lo + t; i < hi; i += 256) {
        int2 p = bpairs[i];
        int l = p.y & 255;
        int pos = lo + loff[l] + atomicAdd(&lcur[l], 1);
        ssrc[pos] = p.x;
    }
}

// ---------------- transform: t2[lane>>3][row][lane&7] = ((in[row] @ W) * inv[row])[lane] ----
// Scalar-broadcast GEMM (round 8): W column in 64 VGPRs, readlane k-broadcast,
// no LDS, no spill. Output written in slice-major layout for the aggregate.

__global__ void __launch_bounds__(256, 2)
k_transform(const float* __restrict__ in, const float* __restrict__ W,
            const float* __restrict__ inv, float* __restrict__ out, int n) {
    const int lane = threadIdx.x & 63;
    const int wid = blockIdx.x * 4 + (threadIdx.x >> 6);
    const int nw = gridDim.x * 4;
    const int g = lane >> 3, f = lane & 7;

    float w[64];
    #pragma unroll
    for (int k = 0; k < 64; ++k) w[k] = W[k * 64 + lane];

    for (int base = wid * 8; base < n; base += nw * 8) {
        float xr[8];
        #pragma unroll
        for (int r = 0; r < 8; ++r) {
            int row = base + r;                               // wave-uniform
            xr[r] = (row < n) ? in[(size_t)row * 64 + lane] : 0.f;
        }
        float acc[8] = {0.f, 0.f, 0.f, 0.f, 0.f, 0.f, 0.f, 0.f};
        #pragma unroll
        for (int r = 0; r < 8; ++r) {
            int xb = __float_as_int(xr[r]);
            #pragma unroll
            for (int k = 0; k < 64; ++k) {
                float s = __int_as_float(__builtin_amdgcn_readlane(xb, k));
                acc[r] = fmaf(s, w[k], acc[r]);
            }
        }
        #pragma unroll
        for (int r = 0; r < 8; ++r) {
            int row = base + r;
            if (row < n)
                out[((size_t)g * n + row) * 8 + f] = acc[r] * inv[row];
        }
    }
}

// ---------------- aggregation (feature-sliced, XCD-pinned) ----------------
// out[d][slice*8+f] = (sum_e t2[slice][src][f] + t2[slice][d][f]) * inv[d] + b
// slice = blockIdx&7 -> all blocks of a slice land on one XCD (round-robin
// dispatch), keeping that slice's 3.2MB t2 block L2-resident. Per edge: 8
// lanes read 32B; group g8=lane>>3 handles edges j+g8; shfl_xor final reduce.

__global__ void __launch_bounds__(256, 4)
k_aggregate(const float* __restrict__ t2, const int* __restrict__ ssrc,
            const int2* __restrict__ ocnt, const float* __restrict__ inv,
            const float* __restrict__ b, float* __restrict__ out,
            int n, int do_relu) {
    const int lane = threadIdx.x & 63;
    const int slice = blockIdx.x & 7;
    const int w = threadIdx.x >> 6;
    const int wid0 = (blockIdx.x >> 3) * 4 + w;
    const int nwaves = (gridDim.x >> 3) * 4;
    const int g8 = lane >> 3, f = lane & 7;
    const float* __restrict__ ts = t2 + (size_t)slice * n * 8;
    const float bj = b[slice * 8 + f];

    for (int node = wid0; node < n; node += nwaves) {
        const int2 oc = ocnt[node];
        const int start = oc.x, cnt = oc.y;
        float acc = 0.f;
        for (int be = 0; be < cnt; be += 64) {
            int m = cnt - be; if (m > 64) m = 64;
            int myidx = (lane < m) ? ssrc[start + be + lane] : 0;
            int j = 0;
            for (; j + 16 <= m; j += 16) {
                int s0 = __shfl(myidx, j + g8);
                int s1 = __shfl(myidx, j + 8 + g8);
                float v0 = ts[(size_t)s0 * 8 + f];
                float v1 = ts[(size_t)s1 * 8 + f];
                acc += v0 + v1;
            }
            for (; j < m; j += 8) {
                int jj = j + g8;
                int s = __shfl(myidx, jj);
                if (jj < m) acc += ts[(size_t)s * 8 + f];
            }
        }
        // reduce partial sums across the 8 lane-groups
        acc += __shfl_xor(acc, 8);
        acc += __shfl_xor(acc, 16);
        acc += __shfl_xor(acc, 32);
        float selfv = ts[(size_t)node * 8 + f];
        float res = fmaf(acc + selfv, inv[node], bj);
        if (do_relu) res = fmaxf(res, 0.f);
        if (lane < 8)
            out[(size_t)node * 64 + slice * 8 + lane] = res;
    }
}

// ---------------- final projection: out[n][16] = h[n][64] @ Wl[64][16] + bl ----------------

__global__ void k_final(const float* __restrict__ h, const float* __restrict__ Wl,
                        const float* __restrict__ bl, float* __restrict__ out, int n) {
    __shared__ float Ws[64 * 16];
    for (int i = threadIdx.x; i < 64 * 16; i += blockDim.x) Ws[i] = Wl[i];
    __syncthreads();
    const int lane = threadIdx.x & 63;
    const int r = lane >> 4, c = lane & 15;
    const int wid = blockIdx.x * (blockDim.x >> 6) + (threadIdx.x >> 6);
    const int nw = gridDim.x * (blockDim.x >> 6);
    const float blc = bl[c];
    for (int base = wid * 4; base < n; base += nw * 4) {
        int row = base + r;
        if (row < n) {
            float acc = blc;
            #pragma unroll
            for (int kk = 0; kk < 16; ++kk) {
                float4 xv = *reinterpret_cast<const float4*>(h + (size_t)row * 64 + kk * 4);
                acc = fmaf(xv.x, Ws[(kk * 4 + 0) * 16 + c],
                      fmaf(xv.y, Ws[(kk * 4 + 1) * 16 + c],
                      fmaf(xv.z, Ws[(kk * 4 + 2) * 16 + c],
                      fmaf(xv.w, Ws[(kk * 4 + 3) * 16 + c], acc))));
            }
            out[(size_t)row * 16 + c] = acc;
        }
    }
}

// ---------------- host ----------------

extern "C" void kernel_launch(void* const* d_in, const int* in_sizes, int n_in,
                              void* d_out, int out_size, void* d_ws, size_t ws_size,
                              hipStream_t stream) {
    const float* x  = (const float*)d_in[0];
    const int*   ei = (const int*)d_in[1];
    const float* W1 = (const float*)d_in[2];
    const float* b1 = (const float*)d_in[3];
    const float* W2 = (const float*)d_in[4];
    const float* b2 = (const float*)d_in[5];
    const float* Wl = (const float*)d_in[6];
    const float* bl = (const float*)d_in[7];
    float* out = (float*)d_out;

    const int n = in_sizes[0] / 64;
    const int e = in_sizes[1] / 2;
    const int* src = ei;
    const int* dst = ei + e;
    const int nbuck = (n + (1 << BSHIFT) - 1) >> BSHIFT;   // 391 for n=100000
    const int nchunk = (e + 4095) / 4096;

    char* ws = (char*)d_ws;
    size_t off = 0;
    auto alloc = [&](size_t bytes) -> void* {
        void* p = ws + off;
        off += (bytes + (WS_ALIGN - 1)) & ~((size_t)WS_ALIGN - 1);
        return p;
    };
    int*   bhist   = (int*)alloc((size_t)MAXBUCK * 4);
    int*   gbase   = (int*)alloc((size_t)(MAXBUCK + 1) * 4);
    int*   gcursor = (int*)alloc((size_t)MAXBUCK * 4);
    int2*  ocnt    = (int2*)alloc((size_t)n * 8);
    float* inv     = (float*)alloc((size_t)n * 4);
    int*   ssrc    = (int*)alloc((size_t)e * 4);
    float* bufA    = (float*)alloc((size_t)n * 64 * 4);
    float* bufB    = (float*)alloc((size_t)n * 64 * 4);
    int2*  bpairs  = (int2*)bufA;   // alias: bufA unused until transforms

    hipMemsetAsync(bhist, 0, (size_t)MAXBUCK * 4, stream);

    k_bhist<<<nchunk, 256, 0, stream>>>(dst, bhist, e, nbuck);
    k_bscan<<<1, MAXBUCK, 0, stream>>>(bhist, gbase, gcursor, e, nbuck);
    k_partition<<<nchunk, 256, 0, stream>>>(src, dst, gcursor, bpairs, e, nbuck);
    k_bfin<<<nbuck, 256, 0, stream>>>(bpairs, gbase, ocnt, inv, ssrc, n);

    // layer 1: t2 = slice-major (x@W1)*inv ; h1 = relu((sum+self)*inv + b1)
    k_transform<<<1024, 256, 0, stream>>>(x, W1, inv, bufA, n);
    k_aggregate<<<2048, 256, 0, stream>>>(bufA, ssrc, ocnt, inv, b1, bufB, n, 1);
    // layer 2
    k_transform<<<1024, 256, 0, stream>>>(bufB, W2, inv, bufA, n);
    k_aggregate<<<2048, 256, 0, stream>>>(bufA, ssrc, ocnt, inv, b2, bufB, n, 1);
    // readout
    k_final<<<2048, 256, 0, stream>>>(bufB, Wl, bl, out, n);
}

// Round 11
// 269.712 us; speedup vs baseline: 2.0152x; 2.0152x over previous
//
#include <hip/hip_runtime.h>
#include <hip/hip_fp16.h>

// GCN: 2x (h@W -> symmetric-norm neighbor aggregation +bias, relu) -> h@Wl+bl
// N=100000, E=1600000, D=H=64, C=16, fp32 compute (no fp32 MFMA -> VALU).
// Round 11: revert aggregate to round-9 full-row structure (4-deep MLP was
// the win; round-10 slice version tripled time despite 2.7x lower FETCH).
// Shrink gathered bytes instead: t' stored fp16 (row 128B, footprint 12.8MB
// -> doubles per-XCD L2 residency, halves miss bytes). bpairs packed to one
// int (src<<8 | dst&255). Only two fp16 roundings in the whole chain.

#define WS_ALIGN 256
#define BSHIFT 8            // 256 nodes per bucket
#define MAXBUCK 512         // n=100000 -> nbuck=391

// ---------------- CSR build ----------------

// bucket-level histogram: one global atomic per (block,bucket)
__global__ void k_bhist(const int* __restrict__ dst, int* __restrict__ bhist,
                        int e, int nbuck) {
    __shared__ int hist[MAXBUCK];
    const int CH = 4096;
    int base = blockIdx.x * CH;
    int end = base + CH; if (end > e) end = e;
    for (int t = threadIdx.x; t < nbuck; t += blockDim.x) hist[t] = 0;
    __syncthreads();
    for (int i = base + threadIdx.x; i < end; i += blockDim.x)
        atomicAdd(&hist[dst[i] >> BSHIFT], 1);
    __syncthreads();
    for (int t = threadIdx.x; t < nbuck; t += blockDim.x)
        if (hist[t]) atomicAdd(&bhist[t], hist[t]);
}

// single-block exclusive scan of bucket totals -> gbase (nbuck+1), gcursor
__global__ void k_bscan(const int* __restrict__ bhist, int* __restrict__ gbase,
                        int* __restrict__ gcursor, int e, int nbuck) {
    __shared__ int tmp[MAXBUCK];
    int t = threadIdx.x;                      // blockDim = MAXBUCK
    int v = (t < nbuck) ? bhist[t] : 0;
    tmp[t] = v;
    __syncthreads();
    int x = v;
    #pragma unroll
    for (int d = 1; d < MAXBUCK; d <<= 1) {
        int y = (t >= d) ? tmp[t - d] : 0;
        __syncthreads();
        x += y;
        tmp[t] = x;
        __syncthreads();
    }
    if (t < nbuck) { gbase[t] = x - v; gcursor[t] = x - v; }
    if (t == 0) gbase[nbuck] = e;
}

// partition edges into bucket-contiguous regions; pair packed (src<<8 | d&255)
__global__ void k_partition(const int* __restrict__ src, const int* __restrict__ dst,
                            int* __restrict__ gcursor, int* __restrict__ bpairs,
                            int e, int nbuck) {
    __shared__ int hist[MAXBUCK];
    __shared__ int lbase[MAXBUCK];
    const int CH = 4096;
    int base = blockIdx.x * CH;
    int end = base + CH; if (end > e) end = e;
    for (int t = threadIdx.x; t < nbuck; t += blockDim.x) hist[t] = 0;
    __syncthreads();
    for (int i = base + threadIdx.x; i < end; i += blockDim.x)
        atomicAdd(&hist[dst[i] >> BSHIFT], 1);
    __syncthreads();
    for (int t = threadIdx.x; t < nbuck; t += blockDim.x) {
        int c = hist[t];
        lbase[t] = (c > 0) ? atomicAdd(&gcursor[t], c) : 0;
        hist[t] = 0;                              // reuse as local cursor
    }
    __syncthreads();
    for (int i = base + threadIdx.x; i < end; i += blockDim.x) {
        int s = src[i], d = dst[i];
        int b = d >> BSHIFT;
        int p = lbase[b] + atomicAdd(&hist[b], 1);
        bpairs[p] = (s << BSHIFT) | (d & ((1 << BSHIFT) - 1));
    }
}

// per-bucket finalize: node counts (LDS), 256-entry exclusive scan (LDS),
// ocnt/inv global write, then exact scatter with LDS cursors.
__global__ void k_bfin(const int* __restrict__ bpairs, const int* __restrict__ gbase,
                       int2* __restrict__ ocnt, float* __restrict__ inv,
                       int* __restrict__ ssrc, int n) {
    __shared__ int lcnt[256];
    __shared__ int tmp[256];
    __shared__ int loff[256];
    __shared__ int lcur[256];
    const int b = blockIdx.x;
    const int t = threadIdx.x;                 // blockDim = 256
    const int lo = gbase[b];
    const int hi = gbase[b + 1];
    lcnt[t] = 0; lcur[t] = 0;
    __syncthreads();
    for (int i = lo + t; i < hi; i += 256)
        atomicAdd(&lcnt[bpairs[i] & 255], 1);
    __syncthreads();
    // exclusive scan of lcnt
    int v = lcnt[t];
    tmp[t] = v;
    __syncthreads();
    int x = v;
    #pragma unroll
    for (int d = 1; d < 256; d <<= 1) {
        int y = (t >= d) ? tmp[t - d] : 0;
        __syncthreads();
        x += y;
        tmp[t] = x;
        __syncthreads();
    }
    loff[t] = x - v;
    int node = (b << BSHIFT) + t;
    if (node < n) {
        ocnt[node] = make_int2(lo + (x - v), v);
        inv[node] = rsqrtf((float)v + 1.0f);
    }
    __syncthreads();
    for (int i = lo + t; i < hi; i += 256) {
        int p = bpairs[i];
        int l = p & 255;
        int pos = lo + loff[l] + atomicAdd(&lcur[l], 1);
        ssrc[pos] = p >> BSHIFT;
    }
}

// ---------------- transform: t'[row][:] = fp16((in[row][:] @ W) * inv[row]) ----------------
// Scalar-broadcast GEMM (round 8): W column in 64 VGPRs, readlane k-broadcast,
// no LDS, no spill. Output stored fp16 (halves gather bytes downstream).

__global__ void __launch_bounds__(256, 2)
k_transform(const float* __restrict__ in, const float* __restrict__ W,
            const float* __restrict__ inv, __half* __restrict__ out, int n) {
    const int lane = threadIdx.x & 63;
    const int wid = blockIdx.x * 4 + (threadIdx.x >> 6);
    const int nw = gridDim.x * 4;

    float w[64];
    #pragma unroll
    for (int k = 0; k < 64; ++k) w[k] = W[k * 64 + lane];

    for (int base = wid * 8; base < n; base += nw * 8) {
        float xr[8];
        #pragma unroll
        for (int r = 0; r < 8; ++r) {
            int row = base + r;                               // wave-uniform
            xr[r] = (row < n) ? in[(size_t)row * 64 + lane] : 0.f;
        }
        float acc[8] = {0.f, 0.f, 0.f, 0.f, 0.f, 0.f, 0.f, 0.f};
        #pragma unroll
        for (int r = 0; r < 8; ++r) {
            int xb = __float_as_int(xr[r]);
            #pragma unroll
            for (int k = 0; k < 64; ++k) {
                float s = __int_as_float(__builtin_amdgcn_readlane(xb, k));
                acc[r] = fmaf(s, w[k], acc[r]);
            }
        }
        #pragma unroll
        for (int r = 0; r < 8; ++r) {
            int row = base + r;
            if (row < n)
                out[(size_t)row * 64 + lane] = __float2half(acc[r] * inv[row]);
        }
    }
}

// ---------------- aggregation: out[d] = (sum_e t'[src] + t'[d]) * inv[d] + b ----------------
// Round-9 structure (full 128B row per edge, 4-deep independent gathers for
// MLP), fp16 t'. One coalesced index load per 64 edges, readlane broadcast.

__global__ void __launch_bounds__(256, 4)
k_aggregate(const __half* __restrict__ t, const int* __restrict__ ssrc,
            const int2* __restrict__ ocnt, const float* __restrict__ inv,
            const float* __restrict__ b, float* __restrict__ out,
            int n, int do_relu) {
    const int lane = threadIdx.x & 63;
    const int wid = blockIdx.x * (blockDim.x >> 6) + (threadIdx.x >> 6);
    const int nw = gridDim.x * (blockDim.x >> 6);
    const float bj = b[lane];
    for (int node = wid; node < n; node += nw) {
        const int2 oc = ocnt[node];
        const int start = oc.x, cnt = oc.y;
        float acc = 0.f;
        for (int be = 0; be < cnt; be += 64) {
            int m = cnt - be; if (m > 64) m = 64;
            int myidx = (lane < m) ? ssrc[start + be + lane] : 0;
            int j = 0;
            for (; j + 4 <= m; j += 4) {
                int s0 = __builtin_amdgcn_readlane(myidx, j + 0);
                int s1 = __builtin_amdgcn_readlane(myidx, j + 1);
                int s2 = __builtin_amdgcn_readlane(myidx, j + 2);
                int s3 = __builtin_amdgcn_readlane(myidx, j + 3);
                float v0 = __half2float(t[(size_t)s0 * 64 + lane]);
                float v1 = __half2float(t[(size_t)s1 * 64 + lane]);
                float v2 = __half2float(t[(size_t)s2 * 64 + lane]);
                float v3 = __half2float(t[(size_t)s3 * 64 + lane]);
                acc += (v0 + v1) + (v2 + v3);
            }
            for (; j < m; ++j) {
                int s = __builtin_amdgcn_readlane(myidx, j);
                acc += __half2float(t[(size_t)s * 64 + lane]);
            }
        }
        float selfv = __half2float(t[(size_t)node * 64 + lane]);
        float res = fmaf(acc + selfv, inv[node], bj);
        if (do_relu) res = fmaxf(res, 0.f);
        out[(size_t)node * 64 + lane] = res;
    }
}

// ---------------- final projection: out[n][16] = h[n][64] @ Wl[64][16] + bl ----------------

__global__ void k_final(const float* __restrict__ h, const float* __restrict__ Wl,
                        const float* __restrict__ bl, float* __restrict__ out, int n) {
    __shared__ float Ws[64 * 16];
    for (int i = threadIdx.x; i < 64 * 16; i += blockDim.x) Ws[i] = Wl[i];
    __syncthreads();
    const int lane = threadIdx.x & 63;
    const int r = lane >> 4, c = lane & 15;
    const int wid = blockIdx.x * (blockDim.x >> 6) + (threadIdx.x >> 6);
    const int nw = gridDim.x * (blockDim.x >> 6);
    const float blc = bl[c];
    for (int base = wid * 4; base < n; base += nw * 4) {
        int row = base + r;
        if (row < n) {
            float acc = blc;
            #pragma unroll
            for (int kk = 0; kk < 16; ++kk) {
                float4 xv = *reinterpret_cast<const float4*>(h + (size_t)row * 64 + kk * 4);
                acc = fmaf(xv.x, Ws[(kk * 4 + 0) * 16 + c],
                      fmaf(xv.y, Ws[(kk * 4 + 1) * 16 + c],
                      fmaf(xv.z, Ws[(kk * 4 + 2) * 16 + c],
                      fmaf(xv.w, Ws[(kk * 4 + 3) * 16 + c], acc))));
            }
            out[(size_t)row * 16 + c] = acc;
        }
    }
}

// ---------------- host ----------------

extern "C" void kernel_launch(void* const* d_in, const int* in_sizes, int n_in,
                              void* d_out, int out_size, void* d_ws, size_t ws_size,
                              hipStream_t stream) {
    const float* x  = (const float*)d_in[0];
    const int*   ei = (const int*)d_in[1];
    const float* W1 = (const float*)d_in[2];
    const float* b1 = (const float*)d_in[3];
    const float* W2 = (const float*)d_in[4];
    const float* b2 = (const float*)d_in[5];
    const float* Wl = (const float*)d_in[6];
    const float* bl = (const float*)d_in[7];
    float* out = (float*)d_out;

    const int n = in_sizes[0] / 64;
    const int e = in_sizes[1] / 2;
    const int* src = ei;
    const int* dst = ei + e;
    const int nbuck = (n + (1 << BSHIFT) - 1) >> BSHIFT;   // 391 for n=100000
    const int nchunk = (e + 4095) / 4096;

    char* ws = (char*)d_ws;
    size_t off = 0;
    auto alloc = [&](size_t bytes) -> void* {
        void* p = ws + off;
        off += (bytes + (WS_ALIGN - 1)) & ~((size_t)WS_ALIGN - 1);
        return p;
    };
    int*    bhist   = (int*)alloc((size_t)MAXBUCK * 4);
    int*    gbase   = (int*)alloc((size_t)(MAXBUCK + 1) * 4);
    int*    gcursor = (int*)alloc((size_t)MAXBUCK * 4);
    int2*   ocnt    = (int2*)alloc((size_t)n * 8);
    float*  inv     = (float*)alloc((size_t)n * 4);
    int*    ssrc    = (int*)alloc((size_t)e * 4);
    __half* bufA    = (__half*)alloc((size_t)n * 64 * 2);   // t' (fp16)
    float*  bufB    = (float*)alloc((size_t)n * 64 * 4);    // h (fp32)
    int*    bpairs  = (int*)bufA;   // alias: packed pairs (e*4 <= n*64*2)

    hipMemsetAsync(bhist, 0, (size_t)MAXBUCK * 4, stream);

    k_bhist<<<nchunk, 256, 0, stream>>>(dst, bhist, e, nbuck);
    k_bscan<<<1, MAXBUCK, 0, stream>>>(bhist, gbase, gcursor, e, nbuck);
    k_partition<<<nchunk, 256, 0, stream>>>(src, dst, gcursor, bpairs, e, nbuck);
    k_bfin<<<nbuck, 256, 0, stream>>>(bpairs, gbase, ocnt, inv, ssrc, n);

    // layer 1: t' = fp16((x@W1)*inv) ; h1 = relu((sum+self)*inv + b1)
    k_transform<<<1024, 256, 0, stream>>>(x, W1, inv, bufA, n);
    k_aggregate<<<2048, 256, 0, stream>>>(bufA, ssrc, ocnt, inv, b1, bufB, n, 1);
    // layer 2
    k_transform<<<1024, 256, 0, stream>>>(bufB, W2, inv, bufA, n);
    k_aggregate<<<2048, 256, 0, stream>>>(bufA, ssrc, ocnt, inv, b2, bufB, n, 1);
    // readout
    k_final<<<2048, 256, 0, stream>>>(bufB, Wl, bl, out, n);
}

// Round 12
// 264.834 us; speedup vs baseline: 2.0523x; 1.0184x over previous
//
#include <hip/hip_runtime.h>
#include <hip/hip_fp16.h>

// GCN: 2x (h@W -> symmetric-norm neighbor aggregation +bias, relu) -> h@Wl+bl
// N=100000, E=1600000, D=H=64, C=16, fp32 compute (no fp32 MFMA -> VALU).
// Round 12: transform was latency-bound at 4 waves/SIMD (per-SIMD issue 21%,
// 1-(1-.21)^4 = the measured 61% per-CU VALUBusy; grid was only 1024 blocks).
// -> grid 3125 (8 waves/SIMD). Also h buffers now fp16 (aggregate writes
// fp16): halves transform-2 + final reads. t' fp16 (round 11), packed pairs.

#define WS_ALIGN 256
#define BSHIFT 8            // 256 nodes per bucket
#define MAXBUCK 512         // n=100000 -> nbuck=391

// ---------------- CSR build ----------------

// bucket-level histogram: one global atomic per (block,bucket)
__global__ void k_bhist(const int* __restrict__ dst, int* __restrict__ bhist,
                        int e, int nbuck) {
    __shared__ int hist[MAXBUCK];
    const int CH = 4096;
    int base = blockIdx.x * CH;
    int end = base + CH; if (end > e) end = e;
    for (int t = threadIdx.x; t < nbuck; t += blockDim.x) hist[t] = 0;
    __syncthreads();
    for (int i = base + threadIdx.x; i < end; i += blockDim.x)
        atomicAdd(&hist[dst[i] >> BSHIFT], 1);
    __syncthreads();
    for (int t = threadIdx.x; t < nbuck; t += blockDim.x)
        if (hist[t]) atomicAdd(&bhist[t], hist[t]);
}

// single-block exclusive scan of bucket totals -> gbase (nbuck+1), gcursor
__global__ void k_bscan(const int* __restrict__ bhist, int* __restrict__ gbase,
                        int* __restrict__ gcursor, int e, int nbuck) {
    __shared__ int tmp[MAXBUCK];
    int t = threadIdx.x;                      // blockDim = MAXBUCK
    int v = (t < nbuck) ? bhist[t] : 0;
    tmp[t] = v;
    __syncthreads();
    int x = v;
    #pragma unroll
    for (int d = 1; d < MAXBUCK; d <<= 1) {
        int y = (t >= d) ? tmp[t - d] : 0;
        __syncthreads();
        x += y;
        tmp[t] = x;
        __syncthreads();
    }
    if (t < nbuck) { gbase[t] = x - v; gcursor[t] = x - v; }
    if (t == 0) gbase[nbuck] = e;
}

// partition edges into bucket-contiguous regions; pair packed (src<<8 | d&255)
__global__ void k_partition(const int* __restrict__ src, const int* __restrict__ dst,
                            int* __restrict__ gcursor, int* __restrict__ bpairs,
                            int e, int nbuck) {
    __shared__ int hist[MAXBUCK];
    __shared__ int lbase[MAXBUCK];
    const int CH = 4096;
    int base = blockIdx.x * CH;
    int end = base + CH; if (end > e) end = e;
    for (int t = threadIdx.x; t < nbuck; t += blockDim.x) hist[t] = 0;
    __syncthreads();
    for (int i = base + threadIdx.x; i < end; i += blockDim.x)
        atomicAdd(&hist[dst[i] >> BSHIFT], 1);
    __syncthreads();
    for (int t = threadIdx.x; t < nbuck; t += blockDim.x) {
        int c = hist[t];
        lbase[t] = (c > 0) ? atomicAdd(&gcursor[t], c) : 0;
        hist[t] = 0;                              // reuse as local cursor
    }
    __syncthreads();
    for (int i = base + threadIdx.x; i < end; i += blockDim.x) {
        int s = src[i], d = dst[i];
        int b = d >> BSHIFT;
        int p = lbase[b] + atomicAdd(&hist[b], 1);
        bpairs[p] = (s << BSHIFT) | (d & ((1 << BSHIFT) - 1));
    }
}

// per-bucket finalize: node counts (LDS), 256-entry exclusive scan (LDS),
// ocnt/inv global write, then exact scatter with LDS cursors.
__global__ void k_bfin(const int* __restrict__ bpairs, const int* __restrict__ gbase,
                       int2* __restrict__ ocnt, float* __restrict__ inv,
                       int* __restrict__ ssrc, int n) {
    __shared__ int lcnt[256];
    __shared__ int tmp[256];
    __shared__ int loff[256];
    __shared__ int lcur[256];
    const int b = blockIdx.x;
    const int t = threadIdx.x;                 // blockDim = 256
    const int lo = gbase[b];
    const int hi = gbase[b + 1];
    lcnt[t] = 0; lcur[t] = 0;
    __syncthreads();
    for (int i = lo + t; i < hi; i += 256)
        atomicAdd(&lcnt[bpairs[i] & 255], 1);
    __syncthreads();
    // exclusive scan of lcnt
    int v = lcnt[t];
    tmp[t] = v;
    __syncthreads();
    int x = v;
    #pragma unroll
    for (int d = 1; d < 256; d <<= 1) {
        int y = (t >= d) ? tmp[t - d] : 0;
        __syncthreads();
        x += y;
        tmp[t] = x;
        __syncthreads();
    }
    loff[t] = x - v;
    int node = (b << BSHIFT) + t;
    if (node < n) {
        ocnt[node] = make_int2(lo + (x - v), v);
        inv[node] = rsqrtf((float)v + 1.0f);
    }
    __syncthreads();
    for (int i = lo + t; i < hi; i += 256) {
        int p = bpairs[i];
        int l = p & 255;
        int pos = lo + loff[l] + atomicAdd(&lcur[l], 1);
        ssrc[pos] = p >> BSHIFT;
    }
}

// ---------------- transform: t'[row][:] = fp16((in[row][:] @ W) * inv[row]) ----------------
// Scalar-broadcast GEMM: W column in 64 VGPRs, readlane k-broadcast, no LDS,
// no spill. Templated input dtype (layer1: fp32 x, layer2: fp16 h).

__device__ __forceinline__ float ldf(const float* p, size_t i) { return p[i]; }
__device__ __forceinline__ float ldf(const __half* p, size_t i) { return __half2float(p[i]); }

template <typename Tin>
__global__ void __launch_bounds__(256, 2)
k_transform(const Tin* __restrict__ in, const float* __restrict__ W,
            const float* __restrict__ inv, __half* __restrict__ out, int n) {
    const int lane = threadIdx.x & 63;
    const int wid = blockIdx.x * 4 + (threadIdx.x >> 6);
    const int nw = gridDim.x * 4;

    float w[64];
    #pragma unroll
    for (int k = 0; k < 64; ++k) w[k] = W[k * 64 + lane];

    for (int base = wid * 8; base < n; base += nw * 8) {
        float xr[8];
        #pragma unroll
        for (int r = 0; r < 8; ++r) {
            int row = base + r;                               // wave-uniform
            xr[r] = (row < n) ? ldf(in, (size_t)row * 64 + lane) : 0.f;
        }
        float acc[8] = {0.f, 0.f, 0.f, 0.f, 0.f, 0.f, 0.f, 0.f};
        #pragma unroll
        for (int r = 0; r < 8; ++r) {
            int xb = __float_as_int(xr[r]);
            #pragma unroll
            for (int k = 0; k < 64; ++k) {
                float s = __int_as_float(__builtin_amdgcn_readlane(xb, k));
                acc[r] = fmaf(s, w[k], acc[r]);
            }
        }
        #pragma unroll
        for (int r = 0; r < 8; ++r) {
            int row = base + r;
            if (row < n)
                out[(size_t)row * 64 + lane] = __float2half(acc[r] * inv[row]);
        }
    }
}

// ---------------- aggregation: out[d] = fp16((sum_e t'[src] + t'[d]) * inv[d] + b) --------
// Full 128B row per edge, 4-deep independent gathers (MLP), fp16 t', fp16 out.

__global__ void __launch_bounds__(256, 4)
k_aggregate(const __half* __restrict__ t, const int* __restrict__ ssrc,
            const int2* __restrict__ ocnt, const float* __restrict__ inv,
            const float* __restrict__ b, __half* __restrict__ out,
            int n, int do_relu) {
    const int lane = threadIdx.x & 63;
    const int wid = blockIdx.x * (blockDim.x >> 6) + (threadIdx.x >> 6);
    const int nw = gridDim.x * (blockDim.x >> 6);
    const float bj = b[lane];
    for (int node = wid; node < n; node += nw) {
        const int2 oc = ocnt[node];
        const int start = oc.x, cnt = oc.y;
        float acc = 0.f;
        for (int be = 0; be < cnt; be += 64) {
            int m = cnt - be; if (m > 64) m = 64;
            int myidx = (lane < m) ? ssrc[start + be + lane] : 0;
            int j = 0;
            for (; j + 4 <= m; j += 4) {
                int s0 = __builtin_amdgcn_readlane(myidx, j + 0);
                int s1 = __builtin_amdgcn_readlane(myidx, j + 1);
                int s2 = __builtin_amdgcn_readlane(myidx, j + 2);
                int s3 = __builtin_amdgcn_readlane(myidx, j + 3);
                float v0 = __half2float(t[(size_t)s0 * 64 + lane]);
                float v1 = __half2float(t[(size_t)s1 * 64 + lane]);
                float v2 = __half2float(t[(size_t)s2 * 64 + lane]);
                float v3 = __half2float(t[(size_t)s3 * 64 + lane]);
                acc += (v0 + v1) + (v2 + v3);
            }
            for (; j < m; ++j) {
                int s = __builtin_amdgcn_readlane(myidx, j);
                acc += __half2float(t[(size_t)s * 64 + lane]);
            }
        }
        float selfv = __half2float(t[(size_t)node * 64 + lane]);
        float res = fmaf(acc + selfv, inv[node], bj);
        if (do_relu) res = fmaxf(res, 0.f);
        out[(size_t)node * 64 + lane] = __float2half(res);
    }
}

// ---------------- final projection: out[n][16] = h[n][64] @ Wl[64][16] + bl ----------------
// h is fp16: load 8 halves (16B) per iter, unpack via __half2.

__global__ void k_final(const __half* __restrict__ h, const float* __restrict__ Wl,
                        const float* __restrict__ bl, float* __restrict__ out, int n) {
    __shared__ float Ws[64 * 16];
    for (int i = threadIdx.x; i < 64 * 16; i += blockDim.x) Ws[i] = Wl[i];
    __syncthreads();
    const int lane = threadIdx.x & 63;
    const int r = lane >> 4, c = lane & 15;
    const int wid = blockIdx.x * (blockDim.x >> 6) + (threadIdx.x >> 6);
    const int nw = gridDim.x * (blockDim.x >> 6);
    const float blc = bl[c];
    for (int base = wid * 4; base < n; base += nw * 4) {
        int row = base + r;
        if (row < n) {
            float acc = blc;
            const __half* hrow = h + (size_t)row * 64;
            #pragma unroll
            for (int kk = 0; kk < 8; ++kk) {
                float4 raw = *reinterpret_cast<const float4*>(hrow + kk * 8);
                const __half2* hp = reinterpret_cast<const __half2*>(&raw);
                #pragma unroll
                for (int j = 0; j < 4; ++j) {
                    float2 f = __half22float2(hp[j]);
                    acc = fmaf(f.x, Ws[(kk * 8 + 2 * j + 0) * 16 + c],
                          fmaf(f.y, Ws[(kk * 8 + 2 * j + 1) * 16 + c], acc));
                }
            }
            out[(size_t)row * 16 + c] = acc;
        }
    }
}

// ---------------- host ----------------

extern "C" void kernel_launch(void* const* d_in, const int* in_sizes, int n_in,
                              void* d_out, int out_size, void* d_ws, size_t ws_size,
                              hipStream_t stream) {
    const float* x  = (const float*)d_in[0];
    const int*   ei = (const int*)d_in[1];
    const float* W1 = (const float*)d_in[2];
    const float* b1 = (const float*)d_in[3];
    const float* W2 = (const float*)d_in[4];
    const float* b2 = (const float*)d_in[5];
    const float* Wl = (const float*)d_in[6];
    const float* bl = (const float*)d_in[7];
    float* out = (float*)d_out;

    const int n = in_sizes[0] / 64;
    const int e = in_sizes[1] / 2;
    const int* src = ei;
    const int* dst = ei + e;
    const int nbuck = (n + (1 << BSHIFT) - 1) >> BSHIFT;   // 391 for n=100000
    const int nchunk = (e + 4095) / 4096;

    char* ws = (char*)d_ws;
    size_t off = 0;
    auto alloc = [&](size_t bytes) -> void* {
        void* p = ws + off;
        off += (bytes + (WS_ALIGN - 1)) & ~((size_t)WS_ALIGN - 1);
        return p;
    };
    int*    bhist   = (int*)alloc((size_t)MAXBUCK * 4);
    int*    gbase   = (int*)alloc((size_t)(MAXBUCK + 1) * 4);
    int*    gcursor = (int*)alloc((size_t)MAXBUCK * 4);
    int2*   ocnt    = (int2*)alloc((size_t)n * 8);
    float*  inv     = (float*)alloc((size_t)n * 4);
    int*    ssrc    = (int*)alloc((size_t)e * 4);
    __half* bufA    = (__half*)alloc((size_t)n * 64 * 2);   // t' (fp16)
    __half* bufB    = (__half*)alloc((size_t)n * 64 * 2);   // h  (fp16)
    int*    bpairs  = (int*)bufA;   // alias: packed pairs (e*4 <= n*64*2)

    hipMemsetAsync(bhist, 0, (size_t)MAXBUCK * 4, stream);

    k_bhist<<<nchunk, 256, 0, stream>>>(dst, bhist, e, nbuck);
    k_bscan<<<1, MAXBUCK, 0, stream>>>(bhist, gbase, gcursor, e, nbuck);
    k_partition<<<nchunk, 256, 0, stream>>>(src, dst, gcursor, bpairs, e, nbuck);
    k_bfin<<<nbuck, 256, 0, stream>>>(bpairs, gbase, ocnt, inv, ssrc, n);

    const int tgrid = (n / 8 + 3) / 4 + 1;   // ~3126: 1 tile per wave, 8 waves/SIMD
    // layer 1: t' = fp16((x@W1)*inv) ; h1 = fp16(relu((sum+self)*inv + b1))
    k_transform<float><<<tgrid, 256, 0, stream>>>(x, W1, inv, bufA, n);
    k_aggregate<<<2048, 256, 0, stream>>>(bufA, ssrc, ocnt, inv, b1, bufB, n, 1);
    // layer 2
    k_transform<__half><<<tgrid, 256, 0, stream>>>(bufB, W2, inv, bufA, n);
    k_aggregate<<<2048, 256, 0, stream>>>(bufA, ssrc, ocnt, inv, b2, bufB, n, 1);
    // readout
    k_final<<<2048, 256, 0, stream>>>(bufB, Wl, bl, out, n);
}

// Round 13
// 195.199 us; speedup vs baseline: 2.7845x; 1.3567x over previous
//
#include <hip/hip_runtime.h>
#include <hip/hip_fp16.h>

// GCN: 2x (h@W -> symmetric-norm neighbor aggregation +bias, relu) -> h@Wl+bl
// N=100000, E=1600000, D=H=64, C=16.
// Round 13: transforms moved to fp16 MFMA (16x16x32_f16, fp32 accum).
// Round-12 falsified occupancy theory: readlane transform is per-wave
// issue-bound (2 instr/FMA + SGPR hazards) -> 54us floor. MFMA does the
// 64x64 matmul in 8 MFMA/16-row-tile; kernel becomes memory-bound (~8us).
// Fragment layouts: D col=lane&15,row=4*(lane>>4)+reg (m89-verified);
// A/B k = 16*blk + 4*(lane>>4) + j (derived from m162 tr-read map).
// t', h fp16 (rounds 11/12); CSR build: bucketed counting sort (round 9).

#define WS_ALIGN 256
#define BSHIFT 8            // 256 nodes per bucket
#define MAXBUCK 512         // n=100000 -> nbuck=391

typedef _Float16 half8 __attribute__((ext_vector_type(8)));
typedef float floatx4 __attribute__((ext_vector_type(4)));

// ---------------- CSR build ----------------

__global__ void k_bhist(const int* __restrict__ dst, int* __restrict__ bhist,
                        int e, int nbuck) {
    __shared__ int hist[MAXBUCK];
    const int CH = 4096;
    int base = blockIdx.x * CH;
    int end = base + CH; if (end > e) end = e;
    for (int t = threadIdx.x; t < nbuck; t += blockDim.x) hist[t] = 0;
    __syncthreads();
    for (int i = base + threadIdx.x; i < end; i += blockDim.x)
        atomicAdd(&hist[dst[i] >> BSHIFT], 1);
    __syncthreads();
    for (int t = threadIdx.x; t < nbuck; t += blockDim.x)
        if (hist[t]) atomicAdd(&bhist[t], hist[t]);
}

__global__ void k_bscan(const int* __restrict__ bhist, int* __restrict__ gbase,
                        int* __restrict__ gcursor, int e, int nbuck) {
    __shared__ int tmp[MAXBUCK];
    int t = threadIdx.x;                      // blockDim = MAXBUCK
    int v = (t < nbuck) ? bhist[t] : 0;
    tmp[t] = v;
    __syncthreads();
    int x = v;
    #pragma unroll
    for (int d = 1; d < MAXBUCK; d <<= 1) {
        int y = (t >= d) ? tmp[t - d] : 0;
        __syncthreads();
        x += y;
        tmp[t] = x;
        __syncthreads();
    }
    if (t < nbuck) { gbase[t] = x - v; gcursor[t] = x - v; }
    if (t == 0) gbase[nbuck] = e;
}

// partition edges into bucket-contiguous regions; pair packed (src<<8 | d&255)
__global__ void k_partition(const int* __restrict__ src, const int* __restrict__ dst,
                            int* __restrict__ gcursor, int* __restrict__ bpairs,
                            int e, int nbuck) {
    __shared__ int hist[MAXBUCK];
    __shared__ int lbase[MAXBUCK];
    const int CH = 4096;
    int base = blockIdx.x * CH;
    int end = base + CH; if (end > e) end = e;
    for (int t = threadIdx.x; t < nbuck; t += blockDim.x) hist[t] = 0;
    __syncthreads();
    for (int i = base + threadIdx.x; i < end; i += blockDim.x)
        atomicAdd(&hist[dst[i] >> BSHIFT], 1);
    __syncthreads();
    for (int t = threadIdx.x; t < nbuck; t += blockDim.x) {
        int c = hist[t];
        lbase[t] = (c > 0) ? atomicAdd(&gcursor[t], c) : 0;
        hist[t] = 0;                              // reuse as local cursor
    }
    __syncthreads();
    for (int i = base + threadIdx.x; i < end; i += blockDim.x) {
        int s = src[i], d = dst[i];
        int b = d >> BSHIFT;
        int p = lbase[b] + atomicAdd(&hist[b], 1);
        bpairs[p] = (s << BSHIFT) | (d & ((1 << BSHIFT) - 1));
    }
}

// per-bucket finalize: node counts (LDS), 256-entry exclusive scan (LDS),
// ocnt/inv global write, then exact scatter with LDS cursors.
__global__ void k_bfin(const int* __restrict__ bpairs, const int* __restrict__ gbase,
                       int2* __restrict__ ocnt, float* __restrict__ inv,
                       int* __restrict__ ssrc, int n) {
    __shared__ int lcnt[256];
    __shared__ int tmp[256];
    __shared__ int loff[256];
    __shared__ int lcur[256];
    const int b = blockIdx.x;
    const int t = threadIdx.x;                 // blockDim = 256
    const int lo = gbase[b];
    const int hi = gbase[b + 1];
    lcnt[t] = 0; lcur[t] = 0;
    __syncthreads();
    for (int i = lo + t; i < hi; i += 256)
        atomicAdd(&lcnt[bpairs[i] & 255], 1);
    __syncthreads();
    int v = lcnt[t];
    tmp[t] = v;
    __syncthreads();
    int x = v;
    #pragma unroll
    for (int d = 1; d < 256; d <<= 1) {
        int y = (t >= d) ? tmp[t - d] : 0;
        __syncthreads();
        x += y;
        tmp[t] = x;
        __syncthreads();
    }
    loff[t] = x - v;
    int node = (b << BSHIFT) + t;
    if (node < n) {
        ocnt[node] = make_int2(lo + (x - v), v);
        inv[node] = rsqrtf((float)v + 1.0f);
    }
    __syncthreads();
    for (int i = lo + t; i < hi; i += 256) {
        int p = bpairs[i];
        int l = p & 255;
        int pos = lo + loff[l] + atomicAdd(&lcur[l], 1);
        ssrc[pos] = p >> BSHIFT;
    }
}

// ---------------- MFMA transform: t'[row][:] = fp16((in[row][:] @ W) * inv[row]) --------
// Wave = 16 rows x 64 cols. A = in rows (fp16 frags), B = W cast fp16
// (hoisted, L2-hot), D = fp32 acc. 2 K-steps x 4 n-tiles = 8 MFMA per tile.
// A/B frag: elem j in [0,4): k = 32*s + 4*(lane>>4) + j ; j in [4,8): +16.
// D: row = 4*(lane>>4)+reg, col = 16*t + (lane&15).

__device__ __forceinline__ void loadA(const float* in, size_t base, half8& a) {
    float4 lo = *reinterpret_cast<const float4*>(in + base);
    float4 hi = *reinterpret_cast<const float4*>(in + base + 16);
    a[0] = (_Float16)lo.x; a[1] = (_Float16)lo.y; a[2] = (_Float16)lo.z; a[3] = (_Float16)lo.w;
    a[4] = (_Float16)hi.x; a[5] = (_Float16)hi.y; a[6] = (_Float16)hi.z; a[7] = (_Float16)hi.w;
}
__device__ __forceinline__ void loadA(const __half* in, size_t base, half8& a) {
    const _Float16* p = reinterpret_cast<const _Float16*>(in + base);
    #pragma unroll
    for (int j = 0; j < 4; ++j) { a[j] = p[j]; a[4 + j] = p[16 + j]; }
}

template <typename Tin>
__global__ void __launch_bounds__(256, 4)
k_transform(const Tin* __restrict__ in, const float* __restrict__ W,
            const float* __restrict__ inv, __half* __restrict__ out, int n) {
    const int lane = threadIdx.x & 63;
    const int m = lane & 15, g = lane >> 4;
    const int wid = blockIdx.x * 4 + (threadIdx.x >> 6);
    const int nw = gridDim.x * 4;

    // B fragments: bf[t][s] = W-block cols 16t..16t+15, k-rows 32s..32s+31
    half8 bf[4][2];
    #pragma unroll
    for (int t = 0; t < 4; ++t)
        #pragma unroll
        for (int s = 0; s < 2; ++s) {
            #pragma unroll
            for (int j = 0; j < 4; ++j) {
                bf[t][s][j]     = (_Float16)W[(32 * s + 4 * g + j) * 64 + 16 * t + m];
                bf[t][s][4 + j] = (_Float16)W[(32 * s + 16 + 4 * g + j) * 64 + 16 * t + m];
            }
        }

    const int ntile = (n + 15) >> 4;
    for (int tile = wid; tile < ntile; tile += nw) {
        const int rbase = tile << 4;
        int arow = rbase + m; if (arow >= n) arow = n - 1;   // tail clamp (n%16==0 here)
        half8 a[2];
        loadA(in, (size_t)arow * 64 + 0  + 4 * g, a[0]);
        loadA(in, (size_t)arow * 64 + 32 + 4 * g, a[1]);

        floatx4 acc[4] = {{0.f,0.f,0.f,0.f},{0.f,0.f,0.f,0.f},{0.f,0.f,0.f,0.f},{0.f,0.f,0.f,0.f}};
        #pragma unroll
        for (int s = 0; s < 2; ++s)
            #pragma unroll
            for (int t = 0; t < 4; ++t)
                acc[t] = __builtin_amdgcn_mfma_f32_16x16x32_f16(a[s], bf[t][s], acc[t], 0, 0, 0);

        #pragma unroll
        for (int reg = 0; reg < 4; ++reg) {
            int row = rbase + 4 * g + reg;
            if (row < n) {
                float iv = inv[row];
                #pragma unroll
                for (int t = 0; t < 4; ++t)
                    out[(size_t)row * 64 + 16 * t + m] = __float2half(acc[t][reg] * iv);
            }
        }
    }
}

// ---------------- aggregation: out[d] = fp16((sum_e t'[src] + t'[d]) * inv[d] + b) --------

__global__ void __launch_bounds__(256, 4)
k_aggregate(const __half* __restrict__ t, const int* __restrict__ ssrc,
            const int2* __restrict__ ocnt, const float* __restrict__ inv,
            const float* __restrict__ b, __half* __restrict__ out,
            int n, int do_relu) {
    const int lane = threadIdx.x & 63;
    const int wid = blockIdx.x * (blockDim.x >> 6) + (threadIdx.x >> 6);
    const int nw = gridDim.x * (blockDim.x >> 6);
    const float bj = b[lane];
    for (int node = wid; node < n; node += nw) {
        const int2 oc = ocnt[node];
        const int start = oc.x, cnt = oc.y;
        float acc = 0.f;
        for (int be = 0; be < cnt; be += 64) {
            int m = cnt - be; if (m > 64) m = 64;
            int myidx = (lane < m) ? ssrc[start + be + lane] : 0;
            int j = 0;
            for (; j + 4 <= m; j += 4) {
                int s0 = __builtin_amdgcn_readlane(myidx, j + 0);
                int s1 = __builtin_amdgcn_readlane(myidx, j + 1);
                int s2 = __builtin_amdgcn_readlane(myidx, j + 2);
                int s3 = __builtin_amdgcn_readlane(myidx, j + 3);
                float v0 = __half2float(t[(size_t)s0 * 64 + lane]);
                float v1 = __half2float(t[(size_t)s1 * 64 + lane]);
                float v2 = __half2float(t[(size_t)s2 * 64 + lane]);
                float v3 = __half2float(t[(size_t)s3 * 64 + lane]);
                acc += (v0 + v1) + (v2 + v3);
            }
            for (; j < m; ++j) {
                int s = __builtin_amdgcn_readlane(myidx, j);
                acc += __half2float(t[(size_t)s * 64 + lane]);
            }
        }
        float selfv = __half2float(t[(size_t)node * 64 + lane]);
        float res = fmaf(acc + selfv, inv[node], bj);
        if (do_relu) res = fmaxf(res, 0.f);
        out[(size_t)node * 64 + lane] = __float2half(res);
    }
}

// ---------------- final projection: out[n][16] = h[n][64] @ Wl[64][16] + bl ----------------

__global__ void k_final(const __half* __restrict__ h, const float* __restrict__ Wl,
                        const float* __restrict__ bl, float* __restrict__ out, int n) {
    __shared__ float Ws[64 * 16];
    for (int i = threadIdx.x; i < 64 * 16; i += blockDim.x) Ws[i] = Wl[i];
    __syncthreads();
    const int lane = threadIdx.x & 63;
    const int r = lane >> 4, c = lane & 15;
    const int wid = blockIdx.x * (blockDim.x >> 6) + (threadIdx.x >> 6);
    const int nw = gridDim.x * (blockDim.x >> 6);
    const float blc = bl[c];
    for (int base = wid * 4; base < n; base += nw * 4) {
        int row = base + r;
        if (row < n) {
            float acc = blc;
            const __half* hrow = h + (size_t)row * 64;
            #pragma unroll
            for (int kk = 0; kk < 8; ++kk) {
                float4 raw = *reinterpret_cast<const float4*>(hrow + kk * 8);
                const __half2* hp = reinterpret_cast<const __half2*>(&raw);
                #pragma unroll
                for (int j = 0; j < 4; ++j) {
                    float2 f = __half22float2(hp[j]);
                    acc = fmaf(f.x, Ws[(kk * 8 + 2 * j + 0) * 16 + c],
                          fmaf(f.y, Ws[(kk * 8 + 2 * j + 1) * 16 + c], acc));
                }
            }
            out[(size_t)row * 16 + c] = acc;
        }
    }
}

// ---------------- host ----------------

extern "C" void kernel_launch(void* const* d_in, const int* in_sizes, int n_in,
                              void* d_out, int out_size, void* d_ws, size_t ws_size,
                              hipStream_t stream) {
    const float* x  = (const float*)d_in[0];
    const int*   ei = (const int*)d_in[1];
    const float* W1 = (const float*)d_in[2];
    const float* b1 = (const float*)d_in[3];
    const float* W2 = (const float*)d_in[4];
    const float* b2 = (const float*)d_in[5];
    const float* Wl = (const float*)d_in[6];
    const float* bl = (const float*)d_in[7];
    float* out = (float*)d_out;

    const int n = in_sizes[0] / 64;
    const int e = in_sizes[1] / 2;
    const int* src = ei;
    const int* dst = ei + e;
    const int nbuck = (n + (1 << BSHIFT) - 1) >> BSHIFT;   // 391 for n=100000
    const int nchunk = (e + 4095) / 4096;

    char* ws = (char*)d_ws;
    size_t off = 0;
    auto alloc = [&](size_t bytes) -> void* {
        void* p = ws + off;
        off += (bytes + (WS_ALIGN - 1)) & ~((size_t)WS_ALIGN - 1);
        return p;
    };
    int*    bhist   = (int*)alloc((size_t)MAXBUCK * 4);
    int*    gbase   = (int*)alloc((size_t)(MAXBUCK + 1) * 4);
    int*    gcursor = (int*)alloc((size_t)MAXBUCK * 4);
    int2*   ocnt    = (int2*)alloc((size_t)n * 8);
    float*  inv     = (float*)alloc((size_t)n * 4);
    int*    ssrc    = (int*)alloc((size_t)e * 4);
    __half* bufA    = (__half*)alloc((size_t)n * 64 * 2);   // t' (fp16)
    __half* bufB    = (__half*)alloc((size_t)n * 64 * 2);   // h  (fp16)
    int*    bpairs  = (int*)bufA;   // alias: packed pairs (e*4 <= n*64*2)

    hipMemsetAsync(bhist, 0, (size_t)MAXBUCK * 4, stream);

    k_bhist<<<nchunk, 256, 0, stream>>>(dst, bhist, e, nbuck);
    k_bscan<<<1, MAXBUCK, 0, stream>>>(bhist, gbase, gcursor, e, nbuck);
    k_partition<<<nchunk, 256, 0, stream>>>(src, dst, gcursor, bpairs, e, nbuck);
    k_bfin<<<nbuck, 256, 0, stream>>>(bpairs, gbase, ocnt, inv, ssrc, n);

    const int ntile = (n + 15) / 16;
    const int tgrid = (ntile + 3) / 4;        // 1 tile per wave, 4 waves/block
    // layer 1: t' = fp16((x@W1)*inv) ; h1 = fp16(relu((sum+self)*inv + b1))
    k_transform<float><<<tgrid, 256, 0, stream>>>(x, W1, inv, bufA, n);
    k_aggregate<<<2048, 256, 0, stream>>>(bufA, ssrc, ocnt, inv, b1, bufB, n, 1);
    // layer 2
    k_transform<__half><<<tgrid, 256, 0, stream>>>(bufB, W2, inv, bufA, n);
    k_aggregate<<<2048, 256, 0, stream>>>(bufA, ssrc, ocnt, inv, b2, bufB, n, 1);
    // readout
    k_final<<<2048, 256, 0, stream>>>(bufB, Wl, bl, out, n);
}

// Round 14
// 181.798 us; speedup vs baseline: 2.9898x; 1.0737x over previous
//
#include <hip/hip_runtime.h>
#include <hip/hip_fp16.h>

// GCN: 2x (h@W -> symmetric-norm neighbor aggregation +bias, relu) -> h@Wl+bl
// N=100000, E=1600000, D=H=64, C=16.
// Round 14: 8-edges-per-VMEM aggregate. Evidence (r9 fp32 vs r13 fp16):
// halving gather bytes+lines gave only -22% -> aggregate is gather-
// INSTRUCTION/latency-slot bound, not byte-bound. fp16 row = 128B = 8 lanes
// x float4, so one wave instr fetches 8 edges (lane = 8*slot + feat_octet):
// 1 bpermute + 1 dwordx4 per 8 edges (was 8 loads + 8 readlanes). Self-loop
// folded in as edge #cnt via tail-mask fma. shfl_xor(8/16/32) slot reduce.
// Transforms: fp16 MFMA 16x16x32 (r13). CSR: bucketed counting sort (r9).

#define WS_ALIGN 256
#define BSHIFT 8            // 256 nodes per bucket
#define MAXBUCK 512         // n=100000 -> nbuck=391

typedef _Float16 half8 __attribute__((ext_vector_type(8)));
typedef float floatx4 __attribute__((ext_vector_type(4)));

// ---------------- CSR build ----------------

__global__ void k_bhist(const int* __restrict__ dst, int* __restrict__ bhist,
                        int e, int nbuck) {
    __shared__ int hist[MAXBUCK];
    const int CH = 4096;
    int base = blockIdx.x * CH;
    int end = base + CH; if (end > e) end = e;
    for (int t = threadIdx.x; t < nbuck; t += blockDim.x) hist[t] = 0;
    __syncthreads();
    for (int i = base + threadIdx.x; i < end; i += blockDim.x)
        atomicAdd(&hist[dst[i] >> BSHIFT], 1);
    __syncthreads();
    for (int t = threadIdx.x; t < nbuck; t += blockDim.x)
        if (hist[t]) atomicAdd(&bhist[t], hist[t]);
}

__global__ void k_bscan(const int* __restrict__ bhist, int* __restrict__ gbase,
                        int* __restrict__ gcursor, int e, int nbuck) {
    __shared__ int tmp[MAXBUCK];
    int t = threadIdx.x;                      // blockDim = MAXBUCK
    int v = (t < nbuck) ? bhist[t] : 0;
    tmp[t] = v;
    __syncthreads();
    int x = v;
    #pragma unroll
    for (int d = 1; d < MAXBUCK; d <<= 1) {
        int y = (t >= d) ? tmp[t - d] : 0;
        __syncthreads();
        x += y;
        tmp[t] = x;
        __syncthreads();
    }
    if (t < nbuck) { gbase[t] = x - v; gcursor[t] = x - v; }
    if (t == 0) gbase[nbuck] = e;
}

// partition edges into bucket-contiguous regions; pair packed (src<<8 | d&255)
__global__ void k_partition(const int* __restrict__ src, const int* __restrict__ dst,
                            int* __restrict__ gcursor, int* __restrict__ bpairs,
                            int e, int nbuck) {
    __shared__ int hist[MAXBUCK];
    __shared__ int lbase[MAXBUCK];
    const int CH = 4096;
    int base = blockIdx.x * CH;
    int end = base + CH; if (end > e) end = e;
    for (int t = threadIdx.x; t < nbuck; t += blockDim.x) hist[t] = 0;
    __syncthreads();
    for (int i = base + threadIdx.x; i < end; i += blockDim.x)
        atomicAdd(&hist[dst[i] >> BSHIFT], 1);
    __syncthreads();
    for (int t = threadIdx.x; t < nbuck; t += blockDim.x) {
        int c = hist[t];
        lbase[t] = (c > 0) ? atomicAdd(&gcursor[t], c) : 0;
        hist[t] = 0;                              // reuse as local cursor
    }
    __syncthreads();
    for (int i = base + threadIdx.x; i < end; i += blockDim.x) {
        int s = src[i], d = dst[i];
        int b = d >> BSHIFT;
        int p = lbase[b] + atomicAdd(&hist[b], 1);
        bpairs[p] = (s << BSHIFT) | (d & ((1 << BSHIFT) - 1));
    }
}

// per-bucket finalize: node counts (LDS), 256-entry exclusive scan (LDS),
// ocnt/inv global write, then exact scatter with LDS cursors.
__global__ void k_bfin(const int* __restrict__ bpairs, const int* __restrict__ gbase,
                       int2* __restrict__ ocnt, float* __restrict__ inv,
                       int* __restrict__ ssrc, int n) {
    __shared__ int lcnt[256];
    __shared__ int tmp[256];
    __shared__ int loff[256];
    __shared__ int lcur[256];
    const int b = blockIdx.x;
    const int t = threadIdx.x;                 // blockDim = 256
    const int lo = gbase[b];
    const int hi = gbase[b + 1];
    lcnt[t] = 0; lcur[t] = 0;
    __syncthreads();
    for (int i = lo + t; i < hi; i += 256)
        atomicAdd(&lcnt[bpairs[i] & 255], 1);
    __syncthreads();
    int v = lcnt[t];
    tmp[t] = v;
    __syncthreads();
    int x = v;
    #pragma unroll
    for (int d = 1; d < 256; d <<= 1) {
        int y = (t >= d) ? tmp[t - d] : 0;
        __syncthreads();
        x += y;
        tmp[t] = x;
        __syncthreads();
    }
    loff[t] = x - v;
    int node = (b << BSHIFT) + t;
    if (node < n) {
        ocnt[node] = make_int2(lo + (x - v), v);
        inv[node] = rsqrtf((float)v + 1.0f);
    }
    __syncthreads();
    for (int i = lo + t; i < hi; i += 256) {
        int p = bpairs[i];
        int l = p & 255;
        int pos = lo + loff[l] + atomicAdd(&lcur[l], 1);
        ssrc[pos] = p >> BSHIFT;
    }
}

// ---------------- MFMA transform: t'[row][:] = fp16((in[row][:] @ W) * inv[row]) --------

__device__ __forceinline__ void loadA(const float* in, size_t base, half8& a) {
    float4 lo = *reinterpret_cast<const float4*>(in + base);
    float4 hi = *reinterpret_cast<const float4*>(in + base + 16);
    a[0] = (_Float16)lo.x; a[1] = (_Float16)lo.y; a[2] = (_Float16)lo.z; a[3] = (_Float16)lo.w;
    a[4] = (_Float16)hi.x; a[5] = (_Float16)hi.y; a[6] = (_Float16)hi.z; a[7] = (_Float16)hi.w;
}
__device__ __forceinline__ void loadA(const __half* in, size_t base, half8& a) {
    const _Float16* p = reinterpret_cast<const _Float16*>(in + base);
    #pragma unroll
    for (int j = 0; j < 4; ++j) { a[j] = p[j]; a[4 + j] = p[16 + j]; }
}

template <typename Tin>
__global__ void __launch_bounds__(256, 4)
k_transform(const Tin* __restrict__ in, const float* __restrict__ W,
            const float* __restrict__ inv, __half* __restrict__ out, int n) {
    const int lane = threadIdx.x & 63;
    const int m = lane & 15, g = lane >> 4;
    const int wid = blockIdx.x * 4 + (threadIdx.x >> 6);
    const int nw = gridDim.x * 4;

    half8 bf[4][2];
    #pragma unroll
    for (int t = 0; t < 4; ++t)
        #pragma unroll
        for (int s = 0; s < 2; ++s) {
            #pragma unroll
            for (int j = 0; j < 4; ++j) {
                bf[t][s][j]     = (_Float16)W[(32 * s + 4 * g + j) * 64 + 16 * t + m];
                bf[t][s][4 + j] = (_Float16)W[(32 * s + 16 + 4 * g + j) * 64 + 16 * t + m];
            }
        }

    const int ntile = (n + 15) >> 4;
    for (int tile = wid; tile < ntile; tile += nw) {
        const int rbase = tile << 4;
        int arow = rbase + m; if (arow >= n) arow = n - 1;
        half8 a[2];
        loadA(in, (size_t)arow * 64 + 0  + 4 * g, a[0]);
        loadA(in, (size_t)arow * 64 + 32 + 4 * g, a[1]);

        floatx4 acc[4] = {{0.f,0.f,0.f,0.f},{0.f,0.f,0.f,0.f},{0.f,0.f,0.f,0.f},{0.f,0.f,0.f,0.f}};
        #pragma unroll
        for (int s = 0; s < 2; ++s)
            #pragma unroll
            for (int t = 0; t < 4; ++t)
                acc[t] = __builtin_amdgcn_mfma_f32_16x16x32_f16(a[s], bf[t][s], acc[t], 0, 0, 0);

        #pragma unroll
        for (int reg = 0; reg < 4; ++reg) {
            int row = rbase + 4 * g + reg;
            if (row < n) {
                float iv = inv[row];
                #pragma unroll
                for (int t = 0; t < 4; ++t)
                    out[(size_t)row * 64 + 16 * t + m] = __float2half(acc[t][reg] * iv);
            }
        }
    }
}

// ---------------- aggregation: out[d] = fp16((sum_e t'[src] + t'[d]) * inv[d] + b) --------
// 8 edges per VMEM instr: lane = 8*slot(g) + feature_octet(f); each lane
// loads float4 (8 fp16 feats) of row sidx (bpermute-distributed). Tail and
// self-loop (virtual edge #cnt) handled via wt-masked fma. shfl_xor reduce.

__global__ void __launch_bounds__(256, 8)
k_aggregate(const __half* __restrict__ t, const int* __restrict__ ssrc,
            const int2* __restrict__ ocnt, const float* __restrict__ inv,
            const float* __restrict__ b, __half* __restrict__ out,
            int n, int do_relu) {
    const int lane = threadIdx.x & 63;
    const int g = lane >> 3;        // edge slot 0..7
    const int f = lane & 7;         // feature octet 0..7
    const int wid = blockIdx.x * (blockDim.x >> 6) + (threadIdx.x >> 6);
    const int nw = gridDim.x * (blockDim.x >> 6);
    float b8[8];
    #pragma unroll
    for (int q = 0; q < 8; ++q) b8[q] = b[f * 8 + q];

    for (int node = wid; node < n; node += nw) {
        const int2 oc = ocnt[node];
        const int start = oc.x, cnt = oc.y;
        const int tot = cnt + 1;                    // + self-loop
        float acc[8] = {0.f,0.f,0.f,0.f,0.f,0.f,0.f,0.f};
        for (int be = 0; be < tot; be += 64) {
            int lim = tot - be; if (lim > 64) lim = 64;
            int myidx = (be + lane < cnt) ? ssrc[start + be + lane] : node;
            for (int j = 0; j < lim; j += 8) {
                int epos = j + g;
                int sidx = __shfl(myidx, epos);             // bpermute
                float wt = (epos < lim) ? 1.f : 0.f;
                float4 raw = *reinterpret_cast<const float4*>(t + (size_t)sidx * 64 + f * 8);
                const __half2* hp = reinterpret_cast<const __half2*>(&raw);
                #pragma unroll
                for (int q = 0; q < 4; ++q) {
                    float2 fv = __half22float2(hp[q]);
                    acc[2 * q]     = fmaf(fv.x, wt, acc[2 * q]);
                    acc[2 * q + 1] = fmaf(fv.y, wt, acc[2 * q + 1]);
                }
            }
        }
        #pragma unroll
        for (int off = 8; off < 64; off <<= 1)
            #pragma unroll
            for (int q = 0; q < 8; ++q)
                acc[q] += __shfl_xor(acc[q], off);
        if (g == 0) {
            const float iv = inv[node];
            __half hres[8];
            #pragma unroll
            for (int q = 0; q < 8; ++q) {
                float r = fmaf(acc[q], iv, b8[q]);
                if (do_relu) r = fmaxf(r, 0.f);
                hres[q] = __float2half(r);
            }
            *reinterpret_cast<float4*>(out + (size_t)node * 64 + f * 8) =
                *reinterpret_cast<const float4*>(hres);
        }
    }
}

// ---------------- final projection: out[n][16] = h[n][64] @ Wl[64][16] + bl ----------------

__global__ void k_final(const __half* __restrict__ h, const float* __restrict__ Wl,
                        const float* __restrict__ bl, float* __restrict__ out, int n) {
    __shared__ float Ws[64 * 16];
    for (int i = threadIdx.x; i < 64 * 16; i += blockDim.x) Ws[i] = Wl[i];
    __syncthreads();
    const int lane = threadIdx.x & 63;
    const int r = lane >> 4, c = lane & 15;
    const int wid = blockIdx.x * (blockDim.x >> 6) + (threadIdx.x >> 6);
    const int nw = gridDim.x * (blockDim.x >> 6);
    const float blc = bl[c];
    for (int base = wid * 4; base < n; base += nw * 4) {
        int row = base + r;
        if (row < n) {
            float acc = blc;
            const __half* hrow = h + (size_t)row * 64;
            #pragma unroll
            for (int kk = 0; kk < 8; ++kk) {
                float4 raw = *reinterpret_cast<const float4*>(hrow + kk * 8);
                const __half2* hp = reinterpret_cast<const __half2*>(&raw);
                #pragma unroll
                for (int j = 0; j < 4; ++j) {
                    float2 fv = __half22float2(hp[j]);
                    acc = fmaf(fv.x, Ws[(kk * 8 + 2 * j + 0) * 16 + c],
                          fmaf(fv.y, Ws[(kk * 8 + 2 * j + 1) * 16 + c], acc));
                }
            }
            out[(size_t)row * 16 + c] = acc;
        }
    }
}

// ---------------- host ----------------

extern "C" void kernel_launch(void* const* d_in, const int* in_sizes, int n_in,
                              void* d_out, int out_size, void* d_ws, size_t ws_size,
                              hipStream_t stream) {
    const float* x  = (const float*)d_in[0];
    const int*   ei = (const int*)d_in[1];
    const float* W1 = (const float*)d_in[2];
    const float* b1 = (const float*)d_in[3];
    const float* W2 = (const float*)d_in[4];
    const float* b2 = (const float*)d_in[5];
    const float* Wl = (const float*)d_in[6];
    const float* bl = (const float*)d_in[7];
    float* out = (float*)d_out;

    const int n = in_sizes[0] / 64;
    const int e = in_sizes[1] / 2;
    const int* src = ei;
    const int* dst = ei + e;
    const int nbuck = (n + (1 << BSHIFT) - 1) >> BSHIFT;   // 391 for n=100000
    const int nchunk = (e + 4095) / 4096;

    char* ws = (char*)d_ws;
    size_t off = 0;
    auto alloc = [&](size_t bytes) -> void* {
        void* p = ws + off;
        off += (bytes + (WS_ALIGN - 1)) & ~((size_t)WS_ALIGN - 1);
        return p;
    };
    int*    bhist   = (int*)alloc((size_t)MAXBUCK * 4);
    int*    gbase   = (int*)alloc((size_t)(MAXBUCK + 1) * 4);
    int*    gcursor = (int*)alloc((size_t)MAXBUCK * 4);
    int2*   ocnt    = (int2*)alloc((size_t)n * 8);
    float*  inv     = (float*)alloc((size_t)n * 4);
    int*    ssrc    = (int*)alloc((size_t)e * 4);
    __half* bufA    = (__half*)alloc((size_t)n * 64 * 2);   // t' (fp16)
    __half* bufB    = (__half*)alloc((size_t)n * 64 * 2);   // h  (fp16)
    int*    bpairs  = (int*)bufA;   // alias: packed pairs (e*4 <= n*64*2)

    hipMemsetAsync(bhist, 0, (size_t)MAXBUCK * 4, stream);

    k_bhist<<<nchunk, 256, 0, stream>>>(dst, bhist, e, nbuck);
    k_bscan<<<1, MAXBUCK, 0, stream>>>(bhist, gbase, gcursor, e, nbuck);
    k_partition<<<nchunk, 256, 0, stream>>>(src, dst, gcursor, bpairs, e, nbuck);
    k_bfin<<<nbuck, 256, 0, stream>>>(bpairs, gbase, ocnt, inv, ssrc, n);

    const int ntile = (n + 15) / 16;
    const int tgrid = (ntile + 3) / 4;        // 1 tile per wave, 4 waves/block
    // layer 1: t' = fp16((x@W1)*inv) ; h1 = fp16(relu((sum+self)*inv + b1))
    k_transform<float><<<tgrid, 256, 0, stream>>>(x, W1, inv, bufA, n);
    k_aggregate<<<2048, 256, 0, stream>>>(bufA, ssrc, ocnt, inv, b1, bufB, n, 1);
    // layer 2
    k_transform<__half><<<tgrid, 256, 0, stream>>>(bufB, W2, inv, bufA, n);
    k_aggregate<<<2048, 256, 0, stream>>>(bufA, ssrc, ocnt, inv, b2, bufB, n, 1);
    // readout
    k_final<<<2048, 256, 0, stream>>>(bufB, Wl, bl, out, n);
}

// Round 15
// 178.340 us; speedup vs baseline: 3.0477x; 1.0194x over previous
//
#include <hip/hip_runtime.h>
#include <hip/hip_fp16.h>

// GCN: 2x (h@W -> symmetric-norm neighbor aggregation +bias, relu) -> h@Wl+bl
// N=100000, E=1600000, D=H=64, C=16.
// Round 15: CSR build trimmed (bhist dropped: partition writes fixed-CAP
// bucket regions + spill list, bscan moved after partition for exact ssrc
// layout); k_final fused into aggregate-2 epilogue (in-wave 64x16 projection,
// writes d_out directly). Aggregate: 8 edges/VMEM, fp16 rows (r14) + ocnt
// prefetch. Transforms: fp16 MFMA 16x16x32 (r13).

#define WS_ALIGN 256
#define BSHIFT 8            // 256 nodes per bucket
#define MAXBUCK 512         // n=100000 -> nbuck=391
#define CAP 6144            // bucket region capacity (mean 4092, +32 sigma)

typedef _Float16 half8 __attribute__((ext_vector_type(8)));
typedef float floatx4 __attribute__((ext_vector_type(4)));

// ---------------- CSR build ----------------

// partition edges into fixed-CAP bucket regions (pair packed src<<8|dst&255);
// gcursor accumulates true totals; overflow -> spill list (empty in practice).
__global__ void k_partition(const int* __restrict__ src, const int* __restrict__ dst,
                            int* __restrict__ gcursor, int* __restrict__ spillcnt,
                            int* __restrict__ bpairs, int2* __restrict__ spill,
                            int e, int nbuck) {
    __shared__ int hist[MAXBUCK];
    __shared__ int lbase[MAXBUCK];
    const int CH = 4096;
    int base = blockIdx.x * CH;
    int end = base + CH; if (end > e) end = e;
    for (int t = threadIdx.x; t < nbuck; t += blockDim.x) hist[t] = 0;
    __syncthreads();
    for (int i = base + threadIdx.x; i < end; i += blockDim.x)
        atomicAdd(&hist[dst[i] >> BSHIFT], 1);
    __syncthreads();
    for (int t = threadIdx.x; t < nbuck; t += blockDim.x) {
        int c = hist[t];
        lbase[t] = (c > 0) ? atomicAdd(&gcursor[t], c) : 0;
        hist[t] = 0;                              // reuse as local cursor
    }
    __syncthreads();
    for (int i = base + threadIdx.x; i < end; i += blockDim.x) {
        int s = src[i], d = dst[i];
        int b = d >> BSHIFT;
        int pos = lbase[b] + atomicAdd(&hist[b], 1);
        int packed = (s << BSHIFT) | (d & ((1 << BSHIFT) - 1));
        if (pos < CAP) bpairs[b * CAP + pos] = packed;
        else { int si = atomicAdd(spillcnt, 1); spill[si] = make_int2(b, packed); }
    }
}

// exclusive scan of true bucket totals -> gbase (exact packed ssrc layout)
__global__ void k_bscan(const int* __restrict__ gcursor, int* __restrict__ gbase,
                        int e, int nbuck) {
    __shared__ int tmp[MAXBUCK];
    int t = threadIdx.x;                      // blockDim = MAXBUCK
    int v = (t < nbuck) ? gcursor[t] : 0;
    tmp[t] = v;
    __syncthreads();
    int x = v;
    #pragma unroll
    for (int d = 1; d < MAXBUCK; d <<= 1) {
        int y = (t >= d) ? tmp[t - d] : 0;
        __syncthreads();
        x += y;
        tmp[t] = x;
        __syncthreads();
    }
    if (t < nbuck) gbase[t] = x - v;
    if (t == 0) gbase[nbuck] = e;
}

// per-bucket finalize: node counts (LDS, incl. spill), 256-entry scan,
// ocnt/inv write, exact scatter to packed ssrc (LDS cursors).
__global__ void k_bfin(const int* __restrict__ bpairs, const int* __restrict__ gcursor,
                       const int* __restrict__ gbase, const int* __restrict__ spillcnt,
                       const int2* __restrict__ spill, int2* __restrict__ ocnt,
                       float* __restrict__ inv, int* __restrict__ ssrc, int n) {
    __shared__ int lcnt[256];
    __shared__ int tmp[256];
    __shared__ int loff[256];
    __shared__ int lcur[256];
    const int b = blockIdx.x;
    const int t = threadIdx.x;                 // blockDim = 256
    const int tot = gcursor[b];
    const int reg = (tot < CAP) ? tot : CAP;
    const int rb = b * CAP;
    const int lo = gbase[b];
    const int spn = *spillcnt;
    lcnt[t] = 0; lcur[t] = 0;
    __syncthreads();
    for (int i = t; i < reg; i += 256)
        atomicAdd(&lcnt[bpairs[rb + i] & 255], 1);
    for (int i = t; i < spn; i += 256) {
        int2 sp = spill[i];
        if (sp.x == b) atomicAdd(&lcnt[sp.y & 255], 1);
    }
    __syncthreads();
    int v = lcnt[t];
    tmp[t] = v;
    __syncthreads();
    int x = v;
    #pragma unroll
    for (int d = 1; d < 256; d <<= 1) {
        int y = (t >= d) ? tmp[t - d] : 0;
        __syncthreads();
        x += y;
        tmp[t] = x;
        __syncthreads();
    }
    loff[t] = x - v;
    int node = (b << BSHIFT) + t;
    if (node < n) {
        ocnt[node] = make_int2(lo + (x - v), v);
        inv[node] = rsqrtf((float)v + 1.0f);
    }
    __syncthreads();
    for (int i = t; i < reg; i += 256) {
        int p = bpairs[rb + i];
        int l = p & 255;
        int pos = lo + loff[l] + atomicAdd(&lcur[l], 1);
        ssrc[pos] = p >> BSHIFT;
    }
    for (int i = t; i < spn; i += 256) {
        int2 sp = spill[i];
        if (sp.x == b) {
            int l = sp.y & 255;
            int pos = lo + loff[l] + atomicAdd(&lcur[l], 1);
            ssrc[pos] = sp.y >> BSHIFT;
        }
    }
}

// ---------------- MFMA transform: t'[row][:] = fp16((in[row][:] @ W) * inv[row]) --------

__device__ __forceinline__ void loadA(const float* in, size_t base, half8& a) {
    float4 lo = *reinterpret_cast<const float4*>(in + base);
    float4 hi = *reinterpret_cast<const float4*>(in + base + 16);
    a[0] = (_Float16)lo.x; a[1] = (_Float16)lo.y; a[2] = (_Float16)lo.z; a[3] = (_Float16)lo.w;
    a[4] = (_Float16)hi.x; a[5] = (_Float16)hi.y; a[6] = (_Float16)hi.z; a[7] = (_Float16)hi.w;
}
__device__ __forceinline__ void loadA(const __half* in, size_t base, half8& a) {
    const _Float16* p = reinterpret_cast<const _Float16*>(in + base);
    #pragma unroll
    for (int j = 0; j < 4; ++j) { a[j] = p[j]; a[4 + j] = p[16 + j]; }
}

template <typename Tin>
__global__ void __launch_bounds__(256, 4)
k_transform(const Tin* __restrict__ in, const float* __restrict__ W,
            const float* __restrict__ inv, __half* __restrict__ out, int n) {
    const int lane = threadIdx.x & 63;
    const int m = lane & 15, g = lane >> 4;
    const int wid = blockIdx.x * 4 + (threadIdx.x >> 6);
    const int nw = gridDim.x * 4;

    half8 bf[4][2];
    #pragma unroll
    for (int t = 0; t < 4; ++t)
        #pragma unroll
        for (int s = 0; s < 2; ++s) {
            #pragma unroll
            for (int j = 0; j < 4; ++j) {
                bf[t][s][j]     = (_Float16)W[(32 * s + 4 * g + j) * 64 + 16 * t + m];
                bf[t][s][4 + j] = (_Float16)W[(32 * s + 16 + 4 * g + j) * 64 + 16 * t + m];
            }
        }

    const int ntile = (n + 15) >> 4;
    for (int tile = wid; tile < ntile; tile += nw) {
        const int rbase = tile << 4;
        int arow = rbase + m; if (arow >= n) arow = n - 1;
        half8 a[2];
        loadA(in, (size_t)arow * 64 + 0  + 4 * g, a[0]);
        loadA(in, (size_t)arow * 64 + 32 + 4 * g, a[1]);

        floatx4 acc[4] = {{0.f,0.f,0.f,0.f},{0.f,0.f,0.f,0.f},{0.f,0.f,0.f,0.f},{0.f,0.f,0.f,0.f}};
        #pragma unroll
        for (int s = 0; s < 2; ++s)
            #pragma unroll
            for (int t = 0; t < 4; ++t)
                acc[t] = __builtin_amdgcn_mfma_f32_16x16x32_f16(a[s], bf[t][s], acc[t], 0, 0, 0);

        #pragma unroll
        for (int reg = 0; reg < 4; ++reg) {
            int row = rbase + 4 * g + reg;
            if (row < n) {
                float iv = inv[row];
                #pragma unroll
                for (int t = 0; t < 4; ++t)
                    out[(size_t)row * 64 + 16 * t + m] = __float2half(acc[t][reg] * iv);
            }
        }
    }
}

// ---------------- aggregation (+ optional fused final projection) ----------------
// h = relu((sum_e t'[src] + t'[d]) * inv[d] + b). FINAL=0: write h fp16.
// FINAL=1: out[d][0:16] = h @ Wl + bl written directly (in-wave matvec:
// after slot-reduce every lane holds the full h row; 16 Wl vals/lane in regs,
// 16 fma, shfl_xor(1/2/4) reduce over f, lanes f==0 store float2).

template <int FINAL>
__global__ void __launch_bounds__(256, 8)
k_aggregate(const __half* __restrict__ t, const int* __restrict__ ssrc,
            const int2* __restrict__ ocnt, const float* __restrict__ inv,
            const float* __restrict__ b, const float* __restrict__ Wl,
            const float* __restrict__ bl, __half* __restrict__ outH,
            float* __restrict__ outF, int n) {
    const int lane = threadIdx.x & 63;
    const int g = lane >> 3;        // edge slot 0..7 (and output col pair if FINAL)
    const int f = lane & 7;         // feature octet
    const int wid = blockIdx.x * (blockDim.x >> 6) + (threadIdx.x >> 6);
    const int nw = gridDim.x * (blockDim.x >> 6);
    float b8[8];
    #pragma unroll
    for (int q = 0; q < 8; ++q) b8[q] = b[f * 8 + q];
    float wl0[8], wl1[8];
    float2 bl2 = make_float2(0.f, 0.f);
    if (FINAL) {
        #pragma unroll
        for (int q = 0; q < 8; ++q) {
            wl0[q] = Wl[(f * 8 + q) * 16 + 2 * g];
            wl1[q] = Wl[(f * 8 + q) * 16 + 2 * g + 1];
        }
        bl2 = make_float2(bl[2 * g], bl[2 * g + 1]);
    }

    if (wid >= n) return;
    int2 oc = ocnt[wid];
    for (int node = wid; node < n; node += nw) {
        const int start = oc.x, cnt = oc.y;
        const int nn = node + nw;
        if (nn < n) oc = ocnt[nn];                      // prefetch next
        const int tot = cnt + 1;                        // + self-loop
        float acc[8] = {0.f,0.f,0.f,0.f,0.f,0.f,0.f,0.f};
        for (int be = 0; be < tot; be += 64) {
            int lim = tot - be; if (lim > 64) lim = 64;
            int myidx = (be + lane < cnt) ? ssrc[start + be + lane] : node;
            for (int j = 0; j < lim; j += 8) {
                int epos = j + g;
                int sidx = __shfl(myidx, epos);
                float wt = (epos < lim) ? 1.f : 0.f;
                float4 raw = *reinterpret_cast<const float4*>(t + (size_t)sidx * 64 + f * 8);
                const __half2* hp = reinterpret_cast<const __half2*>(&raw);
                #pragma unroll
                for (int q = 0; q < 4; ++q) {
                    float2 fv = __half22float2(hp[q]);
                    acc[2 * q]     = fmaf(fv.x, wt, acc[2 * q]);
                    acc[2 * q + 1] = fmaf(fv.y, wt, acc[2 * q + 1]);
                }
            }
        }
        #pragma unroll
        for (int off = 8; off < 64; off <<= 1)
            #pragma unroll
            for (int q = 0; q < 8; ++q)
                acc[q] += __shfl_xor(acc[q], off);
        const float iv = inv[node];
        if (!FINAL) {
            if (g == 0) {
                __half hres[8];
                #pragma unroll
                for (int q = 0; q < 8; ++q) {
                    float r = fmaxf(fmaf(acc[q], iv, b8[q]), 0.f);
                    hres[q] = __float2half(r);
                }
                *reinterpret_cast<float4*>(outH + (size_t)node * 64 + f * 8) =
                    *reinterpret_cast<const float4*>(hres);
            }
        } else {
            float res[8];
            #pragma unroll
            for (int q = 0; q < 8; ++q)
                res[q] = fmaxf(fmaf(acc[q], iv, b8[q]), 0.f);
            float p0 = 0.f, p1 = 0.f;
            #pragma unroll
            for (int q = 0; q < 8; ++q) {
                p0 = fmaf(res[q], wl0[q], p0);
                p1 = fmaf(res[q], wl1[q], p1);
            }
            p0 += __shfl_xor(p0, 1); p0 += __shfl_xor(p0, 2); p0 += __shfl_xor(p0, 4);
            p1 += __shfl_xor(p1, 1); p1 += __shfl_xor(p1, 2); p1 += __shfl_xor(p1, 4);
            if (f == 0) {
                float2 o = make_float2(p0 + bl2.x, p1 + bl2.y);
                *reinterpret_cast<float2*>(outF + (size_t)node * 16 + 2 * g) = o;
            }
        }
    }
}

// ---------------- host ----------------

extern "C" void kernel_launch(void* const* d_in, const int* in_sizes, int n_in,
                              void* d_out, int out_size, void* d_ws, size_t ws_size,
                              hipStream_t stream) {
    const float* x  = (const float*)d_in[0];
    const int*   ei = (const int*)d_in[1];
    const float* W1 = (const float*)d_in[2];
    const float* b1 = (const float*)d_in[3];
    const float* W2 = (const float*)d_in[4];
    const float* b2 = (const float*)d_in[5];
    const float* Wl = (const float*)d_in[6];
    const float* bl = (const float*)d_in[7];
    float* out = (float*)d_out;

    const int n = in_sizes[0] / 64;
    const int e = in_sizes[1] / 2;
    const int* src = ei;
    const int* dst = ei + e;
    const int nbuck = (n + (1 << BSHIFT) - 1) >> BSHIFT;   // 391 for n=100000
    const int nchunk = (e + 4095) / 4096;

    char* ws = (char*)d_ws;
    size_t off = 0;
    auto alloc = [&](size_t bytes) -> void* {
        void* p = ws + off;
        off += (bytes + (WS_ALIGN - 1)) & ~((size_t)WS_ALIGN - 1);
        return p;
    };
    int*    gcursor = (int*)alloc((size_t)(MAXBUCK + 1) * 4);  // +1 = spillcnt
    int*    gbase   = (int*)alloc((size_t)(MAXBUCK + 1) * 4);
    int2*   ocnt    = (int2*)alloc((size_t)n * 8);
    float*  inv     = (float*)alloc((size_t)n * 4);
    int*    ssrc    = (int*)alloc((size_t)e * 4);
    __half* bufA    = (__half*)alloc((size_t)n * 64 * 2);   // t' (fp16)
    __half* bufB    = (__half*)alloc((size_t)n * 64 * 2);   // h1 (fp16)
    int*    bpairs  = (int*)bufA;   // alias: nbuck*CAP*4 = 9.6MB <= 12.8MB
    int2*   spill   = (int2*)bufB;  // alias: worst case e*8 = 12.8MB
    int*    spillcnt = gcursor + MAXBUCK;

    hipMemsetAsync(gcursor, 0, (size_t)(MAXBUCK + 1) * 4, stream);

    k_partition<<<nchunk, 256, 0, stream>>>(src, dst, gcursor, spillcnt, bpairs, spill, e, nbuck);
    k_bscan<<<1, MAXBUCK, 0, stream>>>(gcursor, gbase, e, nbuck);
    k_bfin<<<nbuck, 256, 0, stream>>>(bpairs, gcursor, gbase, spillcnt, spill, ocnt, inv, ssrc, n);

    const int ntile = (n + 15) / 16;
    const int tgrid = (ntile + 3) / 4;        // 1 tile per wave, 4 waves/block
    // layer 1: t' = fp16((x@W1)*inv) ; h1 = fp16(relu((sum+self)*inv + b1))
    k_transform<float><<<tgrid, 256, 0, stream>>>(x, W1, inv, bufA, n);
    k_aggregate<0><<<2048, 256, 0, stream>>>(bufA, ssrc, ocnt, inv, b1, Wl, bl, bufB, out, n);
    // layer 2 (+ fused readout)
    k_transform<__half><<<tgrid, 256, 0, stream>>>(bufB, W2, inv, bufA, n);
    k_aggregate<1><<<2048, 256, 0, stream>>>(bufA, ssrc, ocnt, inv, b2, Wl, bl, bufB, out, n);
}

// Round 16
// 174.729 us; speedup vs baseline: 3.1107x; 1.0207x over previous
//
#include <hip/hip_runtime.h>
#include <hip/hip_fp16.h>

// GCN: 2x (h@W -> symmetric-norm neighbor aggregation +bias, relu) -> h@Wl+bl
// N=100000, E=1600000, D=H=64, C=16.
// Round 16: REVERT aggregate to exact round-14 kernel (46us, FETCH 86MB) and
// standalone k_final. Round-15's fused/templated/prefetched aggregate
// regressed to 63us with FETCH 152MB (+76%) -- co-compiled template variants
// perturbed codegen (rule #19 class); cause not attributable to semantics.
// KEEP round-15 CSR build (bhist dropped; partition -> fixed-CAP regions +
// spill list; bscan after partition; bfin scatter) -- that saved ~38us.
// Transforms: fp16 MFMA 16x16x32 (r13). t'/h fp16 (r11/12).

#define WS_ALIGN 256
#define BSHIFT 8            // 256 nodes per bucket
#define MAXBUCK 512         // n=100000 -> nbuck=391
#define CAP 6144            // bucket region capacity (mean 4092, +32 sigma)

typedef _Float16 half8 __attribute__((ext_vector_type(8)));
typedef float floatx4 __attribute__((ext_vector_type(4)));

// ---------------- CSR build ----------------

// partition edges into fixed-CAP bucket regions (pair packed src<<8|dst&255);
// gcursor accumulates true totals; overflow -> spill list (empty in practice).
__global__ void k_partition(const int* __restrict__ src, const int* __restrict__ dst,
                            int* __restrict__ gcursor, int* __restrict__ spillcnt,
                            int* __restrict__ bpairs, int2* __restrict__ spill,
                            int e, int nbuck) {
    __shared__ int hist[MAXBUCK];
    __shared__ int lbase[MAXBUCK];
    const int CH = 4096;
    int base = blockIdx.x * CH;
    int end = base + CH; if (end > e) end = e;
    for (int t = threadIdx.x; t < nbuck; t += blockDim.x) hist[t] = 0;
    __syncthreads();
    for (int i = base + threadIdx.x; i < end; i += blockDim.x)
        atomicAdd(&hist[dst[i] >> BSHIFT], 1);
    __syncthreads();
    for (int t = threadIdx.x; t < nbuck; t += blockDim.x) {
        int c = hist[t];
        lbase[t] = (c > 0) ? atomicAdd(&gcursor[t], c) : 0;
        hist[t] = 0;                              // reuse as local cursor
    }
    __syncthreads();
    for (int i = base + threadIdx.x; i < end; i += blockDim.x) {
        int s = src[i], d = dst[i];
        int b = d >> BSHIFT;
        int pos = lbase[b] + atomicAdd(&hist[b], 1);
        int packed = (s << BSHIFT) | (d & ((1 << BSHIFT) - 1));
        if (pos < CAP) bpairs[b * CAP + pos] = packed;
        else { int si = atomicAdd(spillcnt, 1); spill[si] = make_int2(b, packed); }
    }
}

// exclusive scan of true bucket totals -> gbase (exact packed ssrc layout)
__global__ void k_bscan(const int* __restrict__ gcursor, int* __restrict__ gbase,
                        int e, int nbuck) {
    __shared__ int tmp[MAXBUCK];
    int t = threadIdx.x;                      // blockDim = MAXBUCK
    int v = (t < nbuck) ? gcursor[t] : 0;
    tmp[t] = v;
    __syncthreads();
    int x = v;
    #pragma unroll
    for (int d = 1; d < MAXBUCK; d <<= 1) {
        int y = (t >= d) ? tmp[t - d] : 0;
        __syncthreads();
        x += y;
        tmp[t] = x;
        __syncthreads();
    }
    if (t < nbuck) gbase[t] = x - v;
    if (t == 0) gbase[nbuck] = e;
}

// per-bucket finalize: node counts (LDS, incl. spill), 256-entry scan,
// ocnt/inv write, exact scatter to packed ssrc (LDS cursors).
__global__ void k_bfin(const int* __restrict__ bpairs, const int* __restrict__ gcursor,
                       const int* __restrict__ gbase, const int* __restrict__ spillcnt,
                       const int2* __restrict__ spill, int2* __restrict__ ocnt,
                       float* __restrict__ inv, int* __restrict__ ssrc, int n) {
    __shared__ int lcnt[256];
    __shared__ int tmp[256];
    __shared__ int loff[256];
    __shared__ int lcur[256];
    const int b = blockIdx.x;
    const int t = threadIdx.x;                 // blockDim = 256
    const int tot = gcursor[b];
    const int reg = (tot < CAP) ? tot : CAP;
    const int rb = b * CAP;
    const int lo = gbase[b];
    const int spn = *spillcnt;
    lcnt[t] = 0; lcur[t] = 0;
    __syncthreads();
    for (int i = t; i < reg; i += 256)
        atomicAdd(&lcnt[bpairs[rb + i] & 255], 1);
    for (int i = t; i < spn; i += 256) {
        int2 sp = spill[i];
        if (sp.x == b) atomicAdd(&lcnt[sp.y & 255], 1);
    }
    __syncthreads();
    int v = lcnt[t];
    tmp[t] = v;
    __syncthreads();
    int x = v;
    #pragma unroll
    for (int d = 1; d < 256; d <<= 1) {
        int y = (t >= d) ? tmp[t - d] : 0;
        __syncthreads();
        x += y;
        tmp[t] = x;
        __syncthreads();
    }
    loff[t] = x - v;
    int node = (b << BSHIFT) + t;
    if (node < n) {
        ocnt[node] = make_int2(lo + (x - v), v);
        inv[node] = rsqrtf((float)v + 1.0f);
    }
    __syncthreads();
    for (int i = t; i < reg; i += 256) {
        int p = bpairs[rb + i];
        int l = p & 255;
        int pos = lo + loff[l] + atomicAdd(&lcur[l], 1);
        ssrc[pos] = p >> BSHIFT;
    }
    for (int i = t; i < spn; i += 256) {
        int2 sp = spill[i];
        if (sp.x == b) {
            int l = sp.y & 255;
            int pos = lo + loff[l] + atomicAdd(&lcur[l], 1);
            ssrc[pos] = sp.y >> BSHIFT;
        }
    }
}

// ---------------- MFMA transform: t'[row][:] = fp16((in[row][:] @ W) * inv[row]) --------

__device__ __forceinline__ void loadA(const float* in, size_t base, half8& a) {
    float4 lo = *reinterpret_cast<const float4*>(in + base);
    float4 hi = *reinterpret_cast<const float4*>(in + base + 16);
    a[0] = (_Float16)lo.x; a[1] = (_Float16)lo.y; a[2] = (_Float16)lo.z; a[3] = (_Float16)lo.w;
    a[4] = (_Float16)hi.x; a[5] = (_Float16)hi.y; a[6] = (_Float16)hi.z; a[7] = (_Float16)hi.w;
}
__device__ __forceinline__ void loadA(const __half* in, size_t base, half8& a) {
    const _Float16* p = reinterpret_cast<const _Float16*>(in + base);
    #pragma unroll
    for (int j = 0; j < 4; ++j) { a[j] = p[j]; a[4 + j] = p[16 + j]; }
}

template <typename Tin>
__global__ void __launch_bounds__(256, 4)
k_transform(const Tin* __restrict__ in, const float* __restrict__ W,
            const float* __restrict__ inv, __half* __restrict__ out, int n) {
    const int lane = threadIdx.x & 63;
    const int m = lane & 15, g = lane >> 4;
    const int wid = blockIdx.x * 4 + (threadIdx.x >> 6);
    const int nw = gridDim.x * 4;

    half8 bf[4][2];
    #pragma unroll
    for (int t = 0; t < 4; ++t)
        #pragma unroll
        for (int s = 0; s < 2; ++s) {
            #pragma unroll
            for (int j = 0; j < 4; ++j) {
                bf[t][s][j]     = (_Float16)W[(32 * s + 4 * g + j) * 64 + 16 * t + m];
                bf[t][s][4 + j] = (_Float16)W[(32 * s + 16 + 4 * g + j) * 64 + 16 * t + m];
            }
        }

    const int ntile = (n + 15) >> 4;
    for (int tile = wid; tile < ntile; tile += nw) {
        const int rbase = tile << 4;
        int arow = rbase + m; if (arow >= n) arow = n - 1;
        half8 a[2];
        loadA(in, (size_t)arow * 64 + 0  + 4 * g, a[0]);
        loadA(in, (size_t)arow * 64 + 32 + 4 * g, a[1]);

        floatx4 acc[4] = {{0.f,0.f,0.f,0.f},{0.f,0.f,0.f,0.f},{0.f,0.f,0.f,0.f},{0.f,0.f,0.f,0.f}};
        #pragma unroll
        for (int s = 0; s < 2; ++s)
            #pragma unroll
            for (int t = 0; t < 4; ++t)
                acc[t] = __builtin_amdgcn_mfma_f32_16x16x32_f16(a[s], bf[t][s], acc[t], 0, 0, 0);

        #pragma unroll
        for (int reg = 0; reg < 4; ++reg) {
            int row = rbase + 4 * g + reg;
            if (row < n) {
                float iv = inv[row];
                #pragma unroll
                for (int t = 0; t < 4; ++t)
                    out[(size_t)row * 64 + 16 * t + m] = __float2half(acc[t][reg] * iv);
            }
        }
    }
}

// ---------------- aggregation: out[d] = fp16((sum_e t'[src] + t'[d]) * inv[d] + b) --------
// EXACT round-14 kernel: 8 edges per VMEM instr (lane = 8*slot + feat_octet),
// self-loop as virtual edge via wt-masked fma, shfl_xor slot reduce.

__global__ void __launch_bounds__(256, 8)
k_aggregate(const __half* __restrict__ t, const int* __restrict__ ssrc,
            const int2* __restrict__ ocnt, const float* __restrict__ inv,
            const float* __restrict__ b, __half* __restrict__ out,
            int n, int do_relu) {
    const int lane = threadIdx.x & 63;
    const int g = lane >> 3;        // edge slot 0..7
    const int f = lane & 7;         // feature octet 0..7
    const int wid = blockIdx.x * (blockDim.x >> 6) + (threadIdx.x >> 6);
    const int nw = gridDim.x * (blockDim.x >> 6);
    float b8[8];
    #pragma unroll
    for (int q = 0; q < 8; ++q) b8[q] = b[f * 8 + q];

    for (int node = wid; node < n; node += nw) {
        const int2 oc = ocnt[node];
        const int start = oc.x, cnt = oc.y;
        const int tot = cnt + 1;                    // + self-loop
        float acc[8] = {0.f,0.f,0.f,0.f,0.f,0.f,0.f,0.f};
        for (int be = 0; be < tot; be += 64) {
            int lim = tot - be; if (lim > 64) lim = 64;
            int myidx = (be + lane < cnt) ? ssrc[start + be + lane] : node;
            for (int j = 0; j < lim; j += 8) {
                int epos = j + g;
                int sidx = __shfl(myidx, epos);             // bpermute
                float wt = (epos < lim) ? 1.f : 0.f;
                float4 raw = *reinterpret_cast<const float4*>(t + (size_t)sidx * 64 + f * 8);
                const __half2* hp = reinterpret_cast<const __half2*>(&raw);
                #pragma unroll
                for (int q = 0; q < 4; ++q) {
                    float2 fv = __half22float2(hp[q]);
                    acc[2 * q]     = fmaf(fv.x, wt, acc[2 * q]);
                    acc[2 * q + 1] = fmaf(fv.y, wt, acc[2 * q + 1]);
                }
            }
        }
        #pragma unroll
        for (int off = 8; off < 64; off <<= 1)
            #pragma unroll
            for (int q = 0; q < 8; ++q)
                acc[q] += __shfl_xor(acc[q], off);
        if (g == 0) {
            const float iv = inv[node];
            __half hres[8];
            #pragma unroll
            for (int q = 0; q < 8; ++q) {
                float r = fmaf(acc[q], iv, b8[q]);
                if (do_relu) r = fmaxf(r, 0.f);
                hres[q] = __float2half(r);
            }
            *reinterpret_cast<float4*>(out + (size_t)node * 64 + f * 8) =
                *reinterpret_cast<const float4*>(hres);
        }
    }
}

// ---------------- final projection: out[n][16] = h[n][64] @ Wl[64][16] + bl ----------------

__global__ void k_final(const __half* __restrict__ h, const float* __restrict__ Wl,
                        const float* __restrict__ bl, float* __restrict__ out, int n) {
    __shared__ float Ws[64 * 16];
    for (int i = threadIdx.x; i < 64 * 16; i += blockDim.x) Ws[i] = Wl[i];
    __syncthreads();
    const int lane = threadIdx.x & 63;
    const int r = lane >> 4, c = lane & 15;
    const int wid = blockIdx.x * (blockDim.x >> 6) + (threadIdx.x >> 6);
    const int nw = gridDim.x * (blockDim.x >> 6);
    const float blc = bl[c];
    for (int base = wid * 4; base < n; base += nw * 4) {
        int row = base + r;
        if (row < n) {
            float acc = blc;
            const __half* hrow = h + (size_t)row * 64;
            #pragma unroll
            for (int kk = 0; kk < 8; ++kk) {
                float4 raw = *reinterpret_cast<const float4*>(hrow + kk * 8);
                const __half2* hp = reinterpret_cast<const __half2*>(&raw);
                #pragma unroll
                for (int j = 0; j < 4; ++j) {
                    float2 fv = __half22float2(hp[j]);
                    acc = fmaf(fv.x, Ws[(kk * 8 + 2 * j + 0) * 16 + c],
                          fmaf(fv.y, Ws[(kk * 8 + 2 * j + 1) * 16 + c], acc));
                }
            }
            out[(size_t)row * 16 + c] = acc;
        }
    }
}

// ---------------- host ----------------

extern "C" void kernel_launch(void* const* d_in, const int* in_sizes, int n_in,
                              void* d_out, int out_size, void* d_ws, size_t ws_size,
                              hipStream_t stream) {
    const float* x  = (const float*)d_in[0];
    const int*   ei = (const int*)d_in[1];
    const float* W1 = (const float*)d_in[2];
    const float* b1 = (const float*)d_in[3];
    const float* W2 = (const float*)d_in[4];
    const float* b2 = (const float*)d_in[5];
    const float* Wl = (const float*)d_in[6];
    const float* bl = (const float*)d_in[7];
    float* out = (float*)d_out;

    const int n = in_sizes[0] / 64;
    const int e = in_sizes[1] / 2;
    const int* src = ei;
    const int* dst = ei + e;
    const int nbuck = (n + (1 << BSHIFT) - 1) >> BSHIFT;   // 391 for n=100000
    const int nchunk = (e + 4095) / 4096;

    char* ws = (char*)d_ws;
    size_t off = 0;
    auto alloc = [&](size_t bytes) -> void* {
        void* p = ws + off;
        off += (bytes + (WS_ALIGN - 1)) & ~((size_t)WS_ALIGN - 1);
        return p;
    };
    int*    gcursor = (int*)alloc((size_t)(MAXBUCK + 1) * 4);  // +1 = spillcnt
    int*    gbase   = (int*)alloc((size_t)(MAXBUCK + 1) * 4);
    int2*   ocnt    = (int2*)alloc((size_t)n * 8);
    float*  inv     = (float*)alloc((size_t)n * 4);
    int*    ssrc    = (int*)alloc((size_t)e * 4);
    __half* bufA    = (__half*)alloc((size_t)n * 64 * 2);   // t' (fp16)
    __half* bufB    = (__half*)alloc((size_t)n * 64 * 2);   // h  (fp16)
    int*    bpairs  = (int*)bufA;   // alias: nbuck*CAP*4 = 9.6MB <= 12.8MB
    int2*   spill   = (int2*)bufB;  // alias: used only during CSR build
    int*    spillcnt = gcursor + MAXBUCK;

    hipMemsetAsync(gcursor, 0, (size_t)(MAXBUCK + 1) * 4, stream);

    k_partition<<<nchunk, 256, 0, stream>>>(src, dst, gcursor, spillcnt, bpairs, spill, e, nbuck);
    k_bscan<<<1, MAXBUCK, 0, stream>>>(gcursor, gbase, e, nbuck);
    k_bfin<<<nbuck, 256, 0, stream>>>(bpairs, gcursor, gbase, spillcnt, spill, ocnt, inv, ssrc, n);

    const int ntile = (n + 15) / 16;
    const int tgrid = (ntile + 3) / 4;        // 1 tile per wave, 4 waves/block
    // layer 1: t' = fp16((x@W1)*inv) ; h1 = fp16(relu((sum+self)*inv + b1))
    k_transform<float><<<tgrid, 256, 0, stream>>>(x, W1, inv, bufA, n);
    k_aggregate<<<2048, 256, 0, stream>>>(bufA, ssrc, ocnt, inv, b1, bufB, n, 1);
    // layer 2
    k_transform<__half><<<tgrid, 256, 0, stream>>>(bufB, W2, inv, bufA, n);
    k_aggregate<<<2048, 256, 0, stream>>>(bufA, ssrc, ocnt, inv, b2, bufB, n, 1);
    // readout
    k_final<<<2048, 256, 0, stream>>>(bufB, Wl, bl, out, n);
}